// Round 1
// baseline (1520.581 us; speedup 1.0000x reference)
//
#include <hip/hip_runtime.h>
#include <hip/hip_fp16.h>
#include <stdint.h>

// Problem constants (from reference)
#define NN 100000      // nodes
#define NE 1600000     // edges per set
#define ETOT (NE + NN) // edges + self loops
#define NBUCK ((NN + 127) >> 7)   // 782 destination buckets of 128 nodes

typedef __attribute__((ext_vector_type(8))) short bf16x8;
typedef __attribute__((ext_vector_type(4))) float f32x4;
typedef __attribute__((ext_vector_type(4))) unsigned short us4;

__device__ __forceinline__ float bf2f(unsigned short u) {
    union { unsigned int i; float f; } x; x.i = ((unsigned int)u) << 16; return x.f;
}
__device__ __forceinline__ unsigned short f2bf(float f) {
    union { float f; unsigned int i; } x; x.f = f;
    unsigned int i = x.i;
    return (unsigned short)((i + 0x7FFFu + ((i >> 16) & 1u)) >> 16);
}
// pack two fp16 coefficients into one int
__device__ __forceinline__ int packab(float a, float b) {
    unsigned int ua = __half_as_ushort(__float2half_rn(a));
    unsigned int ub = __half_as_ushort(__float2half_rn(b));
    return (int)(ua | (ub << 16));
}
__device__ __forceinline__ float2 unpackab(int p) {
    float a = __half2float(__ushort_as_half((unsigned short)(p & 0xFFFF)));
    float b = __half2float(__ushort_as_half((unsigned short)(((unsigned int)p) >> 16)));
    return make_float2(a, b);
}

// ---------- CSR build (blockIdx.y = edge set for all merged kernels) ----------
__global__ void k_init_deg(int* deg0, int* deg1) {
    int i = blockIdx.x * 256 + threadIdx.x;
    if (i < NN) { deg0[i] = 1; deg1[i] = 1; }   // self-loop included
}

// 4 edges/thread, int4 load, 4 independent atomic chains, both sets in one grid
__global__ void k_count(const int* col0, const int* col1, int* deg0, int* deg1) {
    int t = blockIdx.x * 256 + threadIdx.x;
    if (t * 4 >= NE) return;
    const int* col = blockIdx.y ? col1 : col0;
    int* deg = blockIdx.y ? deg1 : deg0;
    int4 a = ((const int4*)col)[t];
    atomicAdd(&deg[a.x], 1); atomicAdd(&deg[a.y], 1);
    atomicAdd(&deg[a.z], 1); atomicAdd(&deg[a.w], 1);
}

// block scans 1024 elems (4/thread); writes inclusive scan into rowptr[i+1]
__global__ void k_scan1(const int* deg0, const int* deg1, int* rp0, int* rp1s, int* bsum) {
    __shared__ int s[256];
    const int* deg = blockIdx.y ? deg1 : deg0;
    int* rp = (blockIdx.y ? rp1s : rp0) + 1;
    int* bs = bsum + blockIdx.y * 128;
    int tid = threadIdx.x;
    int base = blockIdx.x * 1024 + tid * 4;
    int v0 = 0, v1 = 0, v2 = 0, v3 = 0;
    if (base + 0 < NN) v0 = deg[base + 0];
    if (base + 1 < NN) v1 = deg[base + 1];
    if (base + 2 < NN) v2 = deg[base + 2];
    if (base + 3 < NN) v3 = deg[base + 3];
    int sum = v0 + v1 + v2 + v3;
    s[tid] = sum; __syncthreads();
    for (int off = 1; off < 256; off <<= 1) {
        int t = (tid >= off) ? s[tid - off] : 0;
        __syncthreads(); s[tid] += t; __syncthreads();
    }
    int run = s[tid] - sum;
    if (base + 0 < NN) { run += v0; rp[base + 0] = run; }
    if (base + 1 < NN) { run += v1; rp[base + 1] = run; }
    if (base + 2 < NN) { run += v2; rp[base + 2] = run; }
    if (base + 3 < NN) { run += v3; rp[base + 3] = run; }
    if (tid == 255) bs[blockIdx.x] = s[255];
}

__global__ void k_scan2(int* bsum, int nb) {  // per-block exclusive scan, 2 sets
    __shared__ int s[128];
    int* bs = bsum + blockIdx.x * 128;
    int tid = threadIdx.x;
    int v = (tid < nb) ? bs[tid] : 0;
    s[tid] = v; __syncthreads();
    for (int off = 1; off < 128; off <<= 1) {
        int t = (tid >= off) ? s[tid - off] : 0;
        __syncthreads(); s[tid] += t; __syncthreads();
    }
    if (tid < nb) bs[tid] = s[tid] - v;
}

__global__ void k_scan3(int* rp0, int* rp1s, const int* bsum) {
    int* rowptr = blockIdx.y ? rp1s : rp0;
    int add = bsum[blockIdx.y * 128 + blockIdx.x];
    int tid = threadIdx.x;
    int base = blockIdx.x * 1024 + tid * 4;
    #pragma unroll
    for (int i = 0; i < 4; i++) {
        int idx = base + i;
        if (idx < NN) rowptr[idx + 1] += add;
    }
    if (blockIdx.x == 0 && tid == 0) rowptr[0] = 0;
}

// self-loop in slot rowptr[c] (a = 1/deg = dis^2, b = 1); init cursor + dis;
// also init bucket cursors bcur[b] = rowptr[b*128] (bucketed scatter pass A start)
__global__ void k_self(const int* rp0, const int* rp1s, const int* deg0, const int* deg1,
                       int2* eo0, int2* eo1, int* cur0, int* cur1, float* dis0, float* dis1,
                       int* bcur0, int* bcur1) {
    int i = blockIdx.x * 256 + threadIdx.x;
    if (i >= NN) return;
    const int* rowptr = blockIdx.y ? rp1s : rp0;
    const int* deg = blockIdx.y ? deg1 : deg0;
    int2* eo = blockIdx.y ? eo1 : eo0;
    int* cursor = blockIdx.y ? cur1 : cur0;
    float* dis = blockIdx.y ? dis1 : dis0;
    int* bcur = blockIdx.y ? bcur1 : bcur0;
    int p = rowptr[i];
    float d = (float)deg[i];
    eo[p] = make_int2(i, packab(1.0f / d, 1.0f));
    cursor[i] = p + 1;
    dis[i] = rsqrtf(d);
    if ((i & 127) == 0) bcur[i >> 7] = p;   // bucket region starts at rowptr[128b]
}

// ---- bucketed edge scatter: pass A ----
// append record into destination-bucket slab (temporally clustered appends ->
// full-line writes, vs the old random 8B scatter's 8x write amplification).
// record: x = r | (c&127)<<17  (r<2^17, c_local 7 bits), y = packab(a,b)
__global__ void k_bucket(const int* ei0, const float* ew0, const int* ei1, const float* ew1,
                         const float* dis0, const float* dis1,
                         int* bcur0, int* bcur1, int2* st0, int2* st1) {
    int e = blockIdx.x * 256 + threadIdx.x;
    if (e >= NE) return;
    const int* er = blockIdx.y ? ei1 : ei0;
    const float* ew = blockIdx.y ? ew1 : ew0;
    const float* dis = blockIdx.y ? dis1 : dis0;
    int* bcur = blockIdx.y ? bcur1 : bcur0;
    int2* st = blockIdx.y ? st1 : st0;
    int r = er[e], c = er[NE + e];
    float a = dis[r] * dis[c];
    float b = fminf(rsqrtf(ew[e]), 1.0f);
    int p = atomicAdd(&bcur[c >> 7], 1);
    st[p] = make_int2(r | ((c & 127) << 17), packab(a, b));
}

// ---- bucketed edge scatter: pass B ----
// one block per bucket; coalesced read of staged records; scatter within the
// bucket's ~17KB final eo window (L2-resident -> lines fill before eviction).
__global__ __launch_bounds__(256) void k_place(const int* rp0, const int* rp1s,
                        const int* bcur0, const int* bcur1,
                        const int2* st0, const int2* st1,
                        int* cur0, int* cur1, int2* eo0, int2* eo1) {
    int b = blockIdx.x;
    const int* rowptr = blockIdx.y ? rp1s : rp0;
    const int* bcur = blockIdx.y ? bcur1 : bcur0;
    const int2* st = blockIdx.y ? st1 : st0;
    int* cur = blockIdx.y ? cur1 : cur0;
    int2* eo = blockIdx.y ? eo1 : eo0;
    int start = rowptr[b << 7];
    int end = bcur[b];                       // final cursor after pass A
    for (int j = start + (int)threadIdx.x; j < end; j += 256) {
        int2 rec = st[j];
        int r = rec.x & 0x1FFFF;
        int c = (b << 7) + ((rec.x >> 17) & 0x7F);
        int p = atomicAdd(&cur[c], 1);
        eo[p] = make_int2(r, rec.y);
    }
}

// ---------- packing ----------
// Xc[N][256] bf16 = [x | d2an | 0-pad]; 4 cols/thread
__global__ void k_packx(const float* x, const float* d2, unsigned short* Xc) {
    int idx = blockIdx.x * 256 + threadIdx.x;   // NN*64 total
    if (idx >= NN * 64) return;
    int r = idx >> 6, k4 = (idx & 63) << 2;
    us4 o;
    if (k4 < 128) {
        float4 v = *(const float4*)(x + (size_t)r * 128 + k4);
        o[0] = f2bf(v.x); o[1] = f2bf(v.y); o[2] = f2bf(v.z); o[3] = f2bf(v.w);
    } else {
        #pragma unroll
        for (int i = 0; i < 4; i++) {
            int k = k4 + i;
            float v = (k < 226) ? d2[(size_t)r * 98 + (k - 128)] : 0.f;
            o[i] = f2bf(v);
        }
    }
    *(us4*)(Xc + (size_t)r * 256 + k4) = o;
}

// All weights packed in one dispatch, MFMA B-fragment order:
// Wf[ks][ct][lane][j] = Worig[c][k], k = ks*32 + (lane>>4)*8 + j, c = ct*16 + (lane&15)
__global__ void k_packw(const float* wn1, const float* wn2,
                        const float* w1a, const float* w1b,
                        const float* w2a, const float* w2b,
                        const float* w3a, const float* w3b,
                        const float* w4a, const float* w4b,
                        unsigned short* Wfnode, unsigned short* WfL) {
    int idx = blockIdx.x * 256 + threadIdx.x;   // 65536 + 4*32768 = 196608
    if (idx < 65536) {
        int j = idx & 7, lane = (idx >> 3) & 63, ct = (idx >> 9) & 15, ks = idx >> 13;
        int k = ks * 32 + (lane >> 4) * 8 + j;
        int c = ct * 16 + (lane & 15);
        float v = 0.f;
        if (k < 226) v = (c < 128) ? wn1[c * 226 + k] : wn2[(c - 128) * 226 + k];
        Wfnode[idx] = f2bf(v);
    } else if (idx < 196608) {
        int li = idx - 65536;
        int set = li >> 15, r = li & 32767;
        const float* wa = (set == 0) ? w1a : (set == 1) ? w2a : (set == 2) ? w3a : w4a;
        const float* wb = (set == 0) ? w1b : (set == 1) ? w2b : (set == 2) ? w3b : w4b;
        int j = r & 7, lane = (r >> 3) & 63, ct = (r >> 9) & 7, ks = r >> 12;
        int k = ks * 32 + (lane >> 4) * 8 + j;
        int c = ct * 16 + (lane & 15);
        float v = (k < 128) ? wa[c * 128 + k] : wb[c * 128 + (k - 128)];
        WfL[li] = f2bf(v);
    }
}

// ---------- aggregation: one wave per node, 16/4/1 ILP tiers ----------
// g1 = sum a_e*S[row_e], g2 = sum b_e*S[row_e]; coefficients in edge record
template <int SRST, int SOFF>
__global__ __launch_bounds__(256) void k_agg(const unsigned short* S,
                                             const int* rowptr, const int2* eg,
                                             unsigned short* G) {
    int c = blockIdx.x * 4 + (threadIdx.x >> 6);
    int lane = threadIdx.x & 63;
    if (c >= NN) return;
    float a0 = 0.f, a1 = 0.f, b0 = 0.f, b1 = 0.f;
    int jb = rowptr[c], je = rowptr[c + 1];
    const unsigned short* Sb = S + SOFF + lane * 2;
    int j = jb;
    for (; j + 16 <= je; j += 16) {
        int2 e[16]; unsigned int u[16];
        #pragma unroll
        for (int i = 0; i < 16; i++) e[i] = eg[j + i];
        #pragma unroll
        for (int i = 0; i < 16; i++)
            u[i] = *(const unsigned int*)(Sb + (size_t)e[i].x * SRST);
        #pragma unroll
        for (int i = 0; i < 16; i++) {
            float2 w = unpackab(e[i].y);
            float x0 = bf2f((unsigned short)(u[i] & 0xFFFF));
            float x1 = bf2f((unsigned short)(u[i] >> 16));
            a0 += w.x * x0; a1 += w.x * x1; b0 += w.y * x0; b1 += w.y * x1;
        }
    }
    for (; j + 4 <= je; j += 4) {
        int2 e[4]; unsigned int u[4];
        #pragma unroll
        for (int i = 0; i < 4; i++) e[i] = eg[j + i];
        #pragma unroll
        for (int i = 0; i < 4; i++)
            u[i] = *(const unsigned int*)(Sb + (size_t)e[i].x * SRST);
        #pragma unroll
        for (int i = 0; i < 4; i++) {
            float2 w = unpackab(e[i].y);
            float x0 = bf2f((unsigned short)(u[i] & 0xFFFF));
            float x1 = bf2f((unsigned short)(u[i] >> 16));
            a0 += w.x * x0; a1 += w.x * x1; b0 += w.y * x0; b1 += w.y * x1;
        }
    }
    for (; j < je; j++) {
        int2 e = eg[j];
        unsigned int u = *(const unsigned int*)(Sb + (size_t)e.x * SRST);
        float2 w = unpackab(e.y);
        float x0 = bf2f((unsigned short)(u & 0xFFFF));
        float x1 = bf2f((unsigned short)(u >> 16));
        a0 += w.x * x0; a1 += w.x * x1; b0 += w.y * x0; b1 += w.y * x1;
    }
    unsigned int* gd = (unsigned int*)(G + (size_t)c * 256);
    gd[lane]      = (unsigned int)f2bf(a0) | ((unsigned int)f2bf(a1) << 16);
    gd[64 + lane] = (unsigned int)f2bf(b0) | ((unsigned int)f2bf(b1) << 16);
}

// ---------- GEMM: C[64 x 128-per-blockIdx.y] = A[N][256] @ Wf, no LDS ----------
// MODE 0: store bf16 plain; 1: store bf16 0.5*relu(T)+0.5*relu(acc); 2: same but f32 to out
template <int MODE>
__global__ __launch_bounds__(256) void k_gemm(const unsigned short* A, int arst,
                                              const unsigned short* Wf, int nct_total,
                                              unsigned short* outB, float* outF,
                                              const unsigned short* T, int orst) {
    int wave = threadIdx.x >> 6, lane = threadIdx.x & 63;
    int m = lane & 15, quad = lane >> 4;
    int row0 = blockIdx.x * 64 + wave * 16;
    int arow = row0 + m;
    bool rowok = arow < NN;
    const unsigned short* Ap = A + (size_t)arow * arst + quad * 8;
    int ctbase = blockIdx.y * 8;
    f32x4 acc[8];
    #pragma unroll
    for (int t = 0; t < 8; t++) acc[t] = (f32x4){0.f, 0.f, 0.f, 0.f};

    #pragma unroll
    for (int ks = 0; ks < 8; ks++) {
        bf16x8 a;
        if (rowok) a = *(const bf16x8*)(Ap + ks * 32);
        else       a = (bf16x8){0, 0, 0, 0, 0, 0, 0, 0};
        const unsigned short* wp = Wf + ((size_t)(ks * nct_total + ctbase) * 64 + lane) * 8;
        #pragma unroll
        for (int t = 0; t < 8; t++) {
            bf16x8 b = *(const bf16x8*)(wp + t * 512);
            acc[t] = __builtin_amdgcn_mfma_f32_16x16x32_bf16(a, b, acc[t], 0, 0, 0);
        }
    }

    int col0 = blockIdx.y * 128;
    #pragma unroll
    for (int t = 0; t < 8; t++) {
        int c = col0 + t * 16 + m;
        #pragma unroll
        for (int rg = 0; rg < 4; rg++) {
            int r = row0 + quad * 4 + rg;
            if (r < NN) {
                float v = acc[t][rg];
                if (MODE == 0) {
                    outB[(size_t)r * orst + c] = f2bf(v);
                } else {
                    float tv = bf2f(T[(size_t)r * 128 + c]);
                    float o = 0.5f * fmaxf(tv, 0.f) + 0.5f * fmaxf(v, 0.f);
                    if (MODE == 1) outB[(size_t)r * orst + c] = f2bf(o);
                    else           outF[(size_t)r * 128 + c] = o;
                }
            }
        }
    }
}

extern "C" void kernel_launch(void* const* d_in, const int* in_sizes, int n_in,
                              void* d_out, int out_size, void* d_ws, size_t ws_size,
                              hipStream_t stream) {
    const float* x      = (const float*)d_in[0];
    const float* d2an   = (const float*)d_in[1];
    const int*   ei0    = (const int*)d_in[2];
    const float* ew0    = (const float*)d_in[3];
    const int*   ei1    = (const int*)d_in[4];
    const float* ew1    = (const float*)d_in[5];
    const float* nodeW1 = (const float*)d_in[6];
    const float* nodeW2 = (const float*)d_in[7];
    const float* W1a = (const float*)d_in[8],  *W1b = (const float*)d_in[9];
    const float* W2a = (const float*)d_in[10], *W2b = (const float*)d_in[11];
    const float* W3a = (const float*)d_in[12], *W3b = (const float*)d_in[13];
    const float* W4a = (const float*)d_in[14], *W4b = (const float*)d_in[15];
    float* out = (float*)d_out;

    // ws carve-out
    char* p = (char*)d_ws;
    auto alloc = [&](size_t bytes) -> char* {
        char* r = p; p += (bytes + 255) & ~(size_t)255; return r;
    };
    unsigned short* bufA   = (unsigned short*)alloc((size_t)NN * 256 * 2); // Xc -> G
    unsigned short* bufB   = (unsigned short*)alloc((size_t)NN * 256 * 2); // staging -> P -> XM
    unsigned short* Tbuf   = (unsigned short*)alloc((size_t)NN * 128 * 2);
    unsigned short* Wfnode = (unsigned short*)alloc(65536 * 2);
    unsigned short* WfL    = (unsigned short*)alloc((size_t)4 * 32768 * 2);
    int*    deg0    = (int*)alloc((size_t)NN * 4);
    int*    deg1    = (int*)alloc((size_t)NN * 4);
    int*    rowptr0 = (int*)alloc((size_t)(NN + 1) * 4);
    int*    rowptr1 = (int*)alloc((size_t)(NN + 1) * 4);
    int*    cur0    = (int*)alloc((size_t)NN * 4);
    int*    cur1    = (int*)alloc((size_t)NN * 4);
    int*    bsum    = (int*)alloc(2 * 128 * 4);
    float*  dis0    = (float*)alloc((size_t)NN * 4);
    float*  dis1    = (float*)alloc((size_t)NN * 4);
    int2*   eo0     = (int2*)alloc((size_t)ETOT * 8);
    int2*   eo1     = (int2*)alloc((size_t)ETOT * 8);
    int*    bcur0   = (int*)alloc((size_t)NBUCK * 4);
    int*    bcur1   = (int*)alloc((size_t)NBUCK * 4);

    // staging slabs alias bufB (27.2MB <= 51.2MB); bufB's first real use
    // (k_gemm<0> writing P) is stream-ordered after k_place consumes staging.
    int2* st0 = (int2*)bufB;
    int2* st1 = st0 + ETOT;

    int nbN  = (NN + 255) / 256;
    int nbE1 = (NE + 255) / 256;          // 1 edge/thread
    int nbE4 = (NE / 4 + 255) / 256;      // 4 edges/thread
    int nbS  = (NN + 1023) / 1024;        // 98 scan blocks
    dim3 gP((NN + 63) / 64, 2);           // P gemm: 256 output cols
    dim3 gL((NN + 63) / 64, 1);           // layer gemms: 128 output cols
    int nbA = (NN + 3) / 4;               // agg: 4 waves/block, 1 wave/node

    // --- CSR build, both sets per dispatch (blockIdx.y = set) ---
    k_init_deg<<<nbN, 256, 0, stream>>>(deg0, deg1);
    k_count<<<dim3(nbE4, 2), 256, 0, stream>>>(ei0 + NE, ei1 + NE, deg0, deg1);
    k_scan1<<<dim3(nbS, 2), 256, 0, stream>>>(deg0, deg1, rowptr0, rowptr1, bsum);
    k_scan2<<<2, 128, 0, stream>>>(bsum, nbS);
    k_scan3<<<dim3(nbS, 2), 256, 0, stream>>>(rowptr0, rowptr1, bsum);
    k_self<<<dim3(nbN, 2), 256, 0, stream>>>(rowptr0, rowptr1, deg0, deg1,
                                             eo0, eo1, cur0, cur1, dis0, dis1,
                                             bcur0, bcur1);
    // bucketed scatter replaces the old k_fill (190us, 8x write-amplified)
    k_bucket<<<dim3(nbE1, 2), 256, 0, stream>>>(ei0, ew0, ei1, ew1,
                                                dis0, dis1, bcur0, bcur1, st0, st1);
    k_place<<<dim3(NBUCK, 2), 256, 0, stream>>>(rowptr0, rowptr1, bcur0, bcur1,
                                                st0, st1, cur0, cur1, eo0, eo1);

    // --- packing ---
    k_packx<<<(NN * 64 + 255) / 256, 256, 0, stream>>>(x, d2an, bufA);
    k_packw<<<768, 256, 0, stream>>>(nodeW1, nodeW2, W1a, W1b, W2a, W2b,
                                     W3a, W3b, W4a, W4b, Wfnode, WfL);

    // --- round 1: P = [x|d2an] @ [nodeW1|nodeW2]^T  (bufA=Xc -> bufB=P) ---
    k_gemm<0><<<gP, 256, 0, stream>>>(bufA, 256, Wfnode, 16, bufB, nullptr, nullptr, 256);
    // layer0 (set0 on x0p): agg -> G(bufA); T = g1@W1a^T+g2@W1b^T
    k_agg<256, 0><<<nbA, 256, 0, stream>>>(bufB, rowptr0, eo0, bufA);
    k_gemm<0><<<gL, 256, 0, stream>>>(bufA, 256, WfL, 8, Tbuf, nullptr, nullptr, 128);
    // layer1 (set1 on x1p): agg -> G(bufA); XM = 0.5relu(T)+0.5relu(g@W2) -> bufB
    k_agg<256, 128><<<nbA, 256, 0, stream>>>(bufB, rowptr1, eo1, bufA);
    k_gemm<1><<<gL, 256, 0, stream>>>(bufA, 256, WfL + 32768, 8, bufB, nullptr, Tbuf, 128);

    // --- round 2 on XM (bufB, stride 128) ---
    k_agg<128, 0><<<nbA, 256, 0, stream>>>(bufB, rowptr0, eo0, bufA);
    k_gemm<0><<<gL, 256, 0, stream>>>(bufA, 256, WfL + 2 * 32768, 8, Tbuf, nullptr, nullptr, 128);
    k_agg<128, 0><<<nbA, 256, 0, stream>>>(bufB, rowptr1, eo1, bufA);
    k_gemm<2><<<gL, 256, 0, stream>>>(bufA, 256, WfL + 3 * 32768, 8, nullptr, out, Tbuf, 128);
}

// Round 3
// 1040.953 us; speedup vs baseline: 1.4608x; 1.4608x over previous
//
#include <hip/hip_runtime.h>
#include <hip/hip_fp16.h>
#include <stdint.h>

// Problem constants (from reference)
#define NN 100000      // nodes
#define NE 1600000     // edges per set
#define ETOT (NE + NN) // edges + self loops

typedef __attribute__((ext_vector_type(8))) short bf16x8;
typedef __attribute__((ext_vector_type(4))) float f32x4;
typedef __attribute__((ext_vector_type(4))) unsigned short us4;

__device__ __forceinline__ float bf2f(unsigned short u) {
    union { unsigned int i; float f; } x; x.i = ((unsigned int)u) << 16; return x.f;
}
__device__ __forceinline__ unsigned short f2bf(float f) {
    union { float f; unsigned int i; } x; x.f = f;
    unsigned int i = x.i;
    return (unsigned short)((i + 0x7FFFu + ((i >> 16) & 1u)) >> 16);
}
// pack two fp16 coefficients into one int
__device__ __forceinline__ int packab(float a, float b) {
    unsigned int ua = __half_as_ushort(__float2half_rn(a));
    unsigned int ub = __half_as_ushort(__float2half_rn(b));
    return (int)(ua | (ub << 16));
}
__device__ __forceinline__ float2 unpackab(int p) {
    float a = __half2float(__ushort_as_half((unsigned short)(p & 0xFFFF)));
    float b = __half2float(__ushort_as_half((unsigned short)(((unsigned int)p) >> 16)));
    return make_float2(a, b);
}

// ---------- CSR build (blockIdx.y = edge set for all merged kernels) ----------
__global__ void k_init_deg(int* deg0, int* deg1) {
    int i = blockIdx.x * 256 + threadIdx.x;
    if (i < NN) { deg0[i] = 1; deg1[i] = 1; }   // self-loop included
}

// 4 edges/thread, int4 load, 4 independent atomic chains, both sets in one grid
__global__ void k_count(const int* col0, const int* col1, int* deg0, int* deg1) {
    int t = blockIdx.x * 256 + threadIdx.x;
    if (t * 4 >= NE) return;
    const int* col = blockIdx.y ? col1 : col0;
    int* deg = blockIdx.y ? deg1 : deg0;
    int4 a = ((const int4*)col)[t];
    atomicAdd(&deg[a.x], 1); atomicAdd(&deg[a.y], 1);
    atomicAdd(&deg[a.z], 1); atomicAdd(&deg[a.w], 1);
}

// block scans 1024 elems (4/thread); writes inclusive scan into rowptr[i+1]
__global__ void k_scan1(const int* deg0, const int* deg1, int* rp0, int* rp1s, int* bsum) {
    __shared__ int s[256];
    const int* deg = blockIdx.y ? deg1 : deg0;
    int* rp = (blockIdx.y ? rp1s : rp0) + 1;
    int* bs = bsum + blockIdx.y * 128;
    int tid = threadIdx.x;
    int base = blockIdx.x * 1024 + tid * 4;
    int v0 = 0, v1 = 0, v2 = 0, v3 = 0;
    if (base + 0 < NN) v0 = deg[base + 0];
    if (base + 1 < NN) v1 = deg[base + 1];
    if (base + 2 < NN) v2 = deg[base + 2];
    if (base + 3 < NN) v3 = deg[base + 3];
    int sum = v0 + v1 + v2 + v3;
    s[tid] = sum; __syncthreads();
    for (int off = 1; off < 256; off <<= 1) {
        int t = (tid >= off) ? s[tid - off] : 0;
        __syncthreads(); s[tid] += t; __syncthreads();
    }
    int run = s[tid] - sum;
    if (base + 0 < NN) { run += v0; rp[base + 0] = run; }
    if (base + 1 < NN) { run += v1; rp[base + 1] = run; }
    if (base + 2 < NN) { run += v2; rp[base + 2] = run; }
    if (base + 3 < NN) { run += v3; rp[base + 3] = run; }
    if (tid == 255) bs[blockIdx.x] = s[255];
}

__global__ void k_scan2(int* bsum, int nb) {  // per-block exclusive scan, 2 sets
    __shared__ int s[128];
    int* bs = bsum + blockIdx.x * 128;
    int tid = threadIdx.x;
    int v = (tid < nb) ? bs[tid] : 0;
    s[tid] = v; __syncthreads();
    for (int off = 1; off < 128; off <<= 1) {
        int t = (tid >= off) ? s[tid - off] : 0;
        __syncthreads(); s[tid] += t; __syncthreads();
    }
    if (tid < nb) bs[tid] = s[tid] - v;
}

__global__ void k_scan3(int* rp0, int* rp1s, const int* bsum) {
    int* rowptr = blockIdx.y ? rp1s : rp0;
    int add = bsum[blockIdx.y * 128 + blockIdx.x];
    int tid = threadIdx.x;
    int base = blockIdx.x * 1024 + tid * 4;
    #pragma unroll
    for (int i = 0; i < 4; i++) {
        int idx = base + i;
        if (idx < NN) rowptr[idx + 1] += add;
    }
    if (blockIdx.x == 0 && tid == 0) rowptr[0] = 0;
}

// self-loop in slot rowptr[c] (a = 1/deg = dis^2, b = 1); init cursor + dis
__global__ void k_self(const int* rp0, const int* rp1s, const int* deg0, const int* deg1,
                       int2* eo0, int2* eo1, int* cur0, int* cur1, float* dis0, float* dis1) {
    int i = blockIdx.x * 256 + threadIdx.x;
    if (i >= NN) return;
    const int* rowptr = blockIdx.y ? rp1s : rp0;
    const int* deg = blockIdx.y ? deg1 : deg0;
    int2* eo = blockIdx.y ? eo1 : eo0;
    int* cursor = blockIdx.y ? cur1 : cur0;
    float* dis = blockIdx.y ? dis1 : dis0;
    int p = rowptr[i];
    float d = (float)deg[i];
    eo[p] = make_int2(i, packab(1.0f / d, 1.0f));
    cursor[i] = p + 1;
    dis[i] = rsqrtf(d);
}

// direct scatter, 4 edges/thread (ILP: 4 independent gather->atomic->store
// chains in flight; the 1-edge/thread version was latency-bound at 1.2TB/s,
// VALUBusy 1.3%). eo store is a single 8B nontemporal ull store (no-allocate
// hint; int2 is not accepted by the builtin).
__global__ void k_fill(const int* ei0, const float* ew0, const int* ei1, const float* ew1,
                       int* cur0, int* cur1, const float* dis0, const float* dis1,
                       int2* eo0, int2* eo1) {
    int t = blockIdx.x * 256 + threadIdx.x;
    if (t * 4 >= NE) return;
    const int* er = blockIdx.y ? ei1 : ei0;
    const float* ew = blockIdx.y ? ew1 : ew0;
    int* cursor = blockIdx.y ? cur1 : cur0;
    const float* dis = blockIdx.y ? dis1 : dis0;
    unsigned long long* eo = (unsigned long long*)(blockIdx.y ? eo1 : eo0);
    int4 r4 = ((const int4*)er)[t];                 // 4 source nodes
    int4 c4 = ((const int4*)(er + NE))[t];          // 4 dest nodes
    float4 w4 = ((const float4*)ew)[t];
    int rr[4] = {r4.x, r4.y, r4.z, r4.w};
    int cc[4] = {c4.x, c4.y, c4.z, c4.w};
    float ww[4] = {w4.x, w4.y, w4.z, w4.w};
    float dr[4], dc[4];
    #pragma unroll
    for (int i = 0; i < 4; i++) { dr[i] = dis[rr[i]]; dc[i] = dis[cc[i]]; }
    unsigned long long rec[4];
    #pragma unroll
    for (int i = 0; i < 4; i++) {
        float a = dr[i] * dc[i];
        float b = fminf(rsqrtf(ww[i]), 1.0f);
        rec[i] = (unsigned long long)(unsigned int)rr[i]
               | ((unsigned long long)(unsigned int)packab(a, b) << 32);
    }
    int p[4];
    #pragma unroll
    for (int i = 0; i < 4; i++) p[i] = atomicAdd(&cursor[cc[i]], 1);
    #pragma unroll
    for (int i = 0; i < 4; i++)
        __builtin_nontemporal_store(rec[i], &eo[p[i]]);
}

// ---------- packing ----------
// Xc[N][256] bf16 = [x | d2an | 0-pad]; 4 cols/thread
__global__ void k_packx(const float* x, const float* d2, unsigned short* Xc) {
    int idx = blockIdx.x * 256 + threadIdx.x;   // NN*64 total
    if (idx >= NN * 64) return;
    int r = idx >> 6, k4 = (idx & 63) << 2;
    us4 o;
    if (k4 < 128) {
        float4 v = *(const float4*)(x + (size_t)r * 128 + k4);
        o[0] = f2bf(v.x); o[1] = f2bf(v.y); o[2] = f2bf(v.z); o[3] = f2bf(v.w);
    } else {
        #pragma unroll
        for (int i = 0; i < 4; i++) {
            int k = k4 + i;
            float v = (k < 226) ? d2[(size_t)r * 98 + (k - 128)] : 0.f;
            o[i] = f2bf(v);
        }
    }
    *(us4*)(Xc + (size_t)r * 256 + k4) = o;
}

// All weights packed in one dispatch, MFMA B-fragment order:
// Wf[ks][ct][lane][j] = Worig[c][k], k = ks*32 + (lane>>4)*8 + j, c = ct*16 + (lane&15)
__global__ void k_packw(const float* wn1, const float* wn2,
                        const float* w1a, const float* w1b,
                        const float* w2a, const float* w2b,
                        const float* w3a, const float* w3b,
                        const float* w4a, const float* w4b,
                        unsigned short* Wfnode, unsigned short* WfL) {
    int idx = blockIdx.x * 256 + threadIdx.x;   // 65536 + 4*32768 = 196608
    if (idx < 65536) {
        int j = idx & 7, lane = (idx >> 3) & 63, ct = (idx >> 9) & 15, ks = idx >> 13;
        int k = ks * 32 + (lane >> 4) * 8 + j;
        int c = ct * 16 + (lane & 15);
        float v = 0.f;
        if (k < 226) v = (c < 128) ? wn1[c * 226 + k] : wn2[(c - 128) * 226 + k];
        Wfnode[idx] = f2bf(v);
    } else if (idx < 196608) {
        int li = idx - 65536;
        int set = li >> 15, r = li & 32767;
        const float* wa = (set == 0) ? w1a : (set == 1) ? w2a : (set == 2) ? w3a : w4a;
        const float* wb = (set == 0) ? w1b : (set == 1) ? w2b : (set == 2) ? w3b : w4b;
        int j = r & 7, lane = (r >> 3) & 63, ct = (r >> 9) & 7, ks = r >> 12;
        int k = ks * 32 + (lane >> 4) * 8 + j;
        int c = ct * 16 + (lane & 15);
        float v = (k < 128) ? wa[c * 128 + k] : wb[c * 128 + (k - 128)];
        WfL[li] = f2bf(v);
    }
}

// ---------- aggregation: one wave per node, 16/4/1 ILP tiers ----------
// g1 = sum a_e*S[row_e], g2 = sum b_e*S[row_e]; coefficients in edge record
template <int SRST, int SOFF>
__global__ __launch_bounds__(256) void k_agg(const unsigned short* S,
                                             const int* rowptr, const int2* eg,
                                             unsigned short* G) {
    int c = blockIdx.x * 4 + (threadIdx.x >> 6);
    int lane = threadIdx.x & 63;
    if (c >= NN) return;
    float a0 = 0.f, a1 = 0.f, b0 = 0.f, b1 = 0.f;
    int jb = rowptr[c], je = rowptr[c + 1];
    const unsigned short* Sb = S + SOFF + lane * 2;
    int j = jb;
    for (; j + 16 <= je; j += 16) {
        int2 e[16]; unsigned int u[16];
        #pragma unroll
        for (int i = 0; i < 16; i++) e[i] = eg[j + i];
        #pragma unroll
        for (int i = 0; i < 16; i++)
            u[i] = *(const unsigned int*)(Sb + (size_t)e[i].x * SRST);
        #pragma unroll
        for (int i = 0; i < 16; i++) {
            float2 w = unpackab(e[i].y);
            float x0 = bf2f((unsigned short)(u[i] & 0xFFFF));
            float x1 = bf2f((unsigned short)(u[i] >> 16));
            a0 += w.x * x0; a1 += w.x * x1; b0 += w.y * x0; b1 += w.y * x1;
        }
    }
    for (; j + 4 <= je; j += 4) {
        int2 e[4]; unsigned int u[4];
        #pragma unroll
        for (int i = 0; i < 4; i++) e[i] = eg[j + i];
        #pragma unroll
        for (int i = 0; i < 4; i++)
            u[i] = *(const unsigned int*)(Sb + (size_t)e[i].x * SRST);
        #pragma unroll
        for (int i = 0; i < 4; i++) {
            float2 w = unpackab(e[i].y);
            float x0 = bf2f((unsigned short)(u[i] & 0xFFFF));
            float x1 = bf2f((unsigned short)(u[i] >> 16));
            a0 += w.x * x0; a1 += w.x * x1; b0 += w.y * x0; b1 += w.y * x1;
        }
    }
    for (; j < je; j++) {
        int2 e = eg[j];
        unsigned int u = *(const unsigned int*)(Sb + (size_t)e.x * SRST);
        float2 w = unpackab(e.y);
        float x0 = bf2f((unsigned short)(u & 0xFFFF));
        float x1 = bf2f((unsigned short)(u >> 16));
        a0 += w.x * x0; a1 += w.x * x1; b0 += w.y * x0; b1 += w.y * x1;
    }
    unsigned int* gd = (unsigned int*)(G + (size_t)c * 256);
    gd[lane]      = (unsigned int)f2bf(a0) | ((unsigned int)f2bf(a1) << 16);
    gd[64 + lane] = (unsigned int)f2bf(b0) | ((unsigned int)f2bf(b1) << 16);
}

// ---------- GEMM: C[64 x 128-per-blockIdx.y] = A[N][256] @ Wf, no LDS ----------
// MODE 0: store bf16 plain; 1: store bf16 0.5*relu(T)+0.5*relu(acc); 2: same but f32 to out
template <int MODE>
__global__ __launch_bounds__(256) void k_gemm(const unsigned short* A, int arst,
                                              const unsigned short* Wf, int nct_total,
                                              unsigned short* outB, float* outF,
                                              const unsigned short* T, int orst) {
    int wave = threadIdx.x >> 6, lane = threadIdx.x & 63;
    int m = lane & 15, quad = lane >> 4;
    int row0 = blockIdx.x * 64 + wave * 16;
    int arow = row0 + m;
    bool rowok = arow < NN;
    const unsigned short* Ap = A + (size_t)arow * arst + quad * 8;
    int ctbase = blockIdx.y * 8;
    f32x4 acc[8];
    #pragma unroll
    for (int t = 0; t < 8; t++) acc[t] = (f32x4){0.f, 0.f, 0.f, 0.f};

    #pragma unroll
    for (int ks = 0; ks < 8; ks++) {
        bf16x8 a;
        if (rowok) a = *(const bf16x8*)(Ap + ks * 32);
        else       a = (bf16x8){0, 0, 0, 0, 0, 0, 0, 0};
        const unsigned short* wp = Wf + ((size_t)(ks * nct_total + ctbase) * 64 + lane) * 8;
        #pragma unroll
        for (int t = 0; t < 8; t++) {
            bf16x8 b = *(const bf16x8*)(wp + t * 512);
            acc[t] = __builtin_amdgcn_mfma_f32_16x16x32_bf16(a, b, acc[t], 0, 0, 0);
        }
    }

    int col0 = blockIdx.y * 128;
    #pragma unroll
    for (int t = 0; t < 8; t++) {
        int c = col0 + t * 16 + m;
        #pragma unroll
        for (int rg = 0; rg < 4; rg++) {
            int r = row0 + quad * 4 + rg;
            if (r < NN) {
                float v = acc[t][rg];
                if (MODE == 0) {
                    outB[(size_t)r * orst + c] = f2bf(v);
                } else {
                    float tv = bf2f(T[(size_t)r * 128 + c]);
                    float o = 0.5f * fmaxf(tv, 0.f) + 0.5f * fmaxf(v, 0.f);
                    if (MODE == 1) outB[(size_t)r * orst + c] = f2bf(o);
                    else           outF[(size_t)r * 128 + c] = o;
                }
            }
        }
    }
}

extern "C" void kernel_launch(void* const* d_in, const int* in_sizes, int n_in,
                              void* d_out, int out_size, void* d_ws, size_t ws_size,
                              hipStream_t stream) {
    const float* x      = (const float*)d_in[0];
    const float* d2an   = (const float*)d_in[1];
    const int*   ei0    = (const int*)d_in[2];
    const float* ew0    = (const float*)d_in[3];
    const int*   ei1    = (const int*)d_in[4];
    const float* ew1    = (const float*)d_in[5];
    const float* nodeW1 = (const float*)d_in[6];
    const float* nodeW2 = (const float*)d_in[7];
    const float* W1a = (const float*)d_in[8],  *W1b = (const float*)d_in[9];
    const float* W2a = (const float*)d_in[10], *W2b = (const float*)d_in[11];
    const float* W3a = (const float*)d_in[12], *W3b = (const float*)d_in[13];
    const float* W4a = (const float*)d_in[14], *W4b = (const float*)d_in[15];
    float* out = (float*)d_out;

    // ws carve-out
    char* p = (char*)d_ws;
    auto alloc = [&](size_t bytes) -> char* {
        char* r = p; p += (bytes + 255) & ~(size_t)255; return r;
    };
    unsigned short* bufA   = (unsigned short*)alloc((size_t)NN * 256 * 2); // Xc -> G
    unsigned short* bufB   = (unsigned short*)alloc((size_t)NN * 256 * 2); // P  -> XM
    unsigned short* Tbuf   = (unsigned short*)alloc((size_t)NN * 128 * 2);
    unsigned short* Wfnode = (unsigned short*)alloc(65536 * 2);
    unsigned short* WfL    = (unsigned short*)alloc((size_t)4 * 32768 * 2);
    int*    deg0    = (int*)alloc((size_t)NN * 4);
    int*    deg1    = (int*)alloc((size_t)NN * 4);
    int*    rowptr0 = (int*)alloc((size_t)(NN + 1) * 4);
    int*    rowptr1 = (int*)alloc((size_t)(NN + 1) * 4);
    int*    cur0    = (int*)alloc((size_t)NN * 4);
    int*    cur1    = (int*)alloc((size_t)NN * 4);
    int*    bsum    = (int*)alloc(2 * 128 * 4);
    float*  dis0    = (float*)alloc((size_t)NN * 4);
    float*  dis1    = (float*)alloc((size_t)NN * 4);
    int2*   eo0     = (int2*)alloc((size_t)ETOT * 8);
    int2*   eo1     = (int2*)alloc((size_t)ETOT * 8);

    int nbN  = (NN + 255) / 256;
    int nbE4 = (NE / 4 + 255) / 256;      // 4 edges/thread
    int nbS  = (NN + 1023) / 1024;        // 98 scan blocks
    dim3 gP((NN + 63) / 64, 2);           // P gemm: 256 output cols
    dim3 gL((NN + 63) / 64, 1);           // layer gemms: 128 output cols
    int nbA = (NN + 3) / 4;               // agg: 4 waves/block, 1 wave/node

    // --- CSR build, both sets per dispatch (blockIdx.y = set) ---
    k_init_deg<<<nbN, 256, 0, stream>>>(deg0, deg1);
    k_count<<<dim3(nbE4, 2), 256, 0, stream>>>(ei0 + NE, ei1 + NE, deg0, deg1);
    k_scan1<<<dim3(nbS, 2), 256, 0, stream>>>(deg0, deg1, rowptr0, rowptr1, bsum);
    k_scan2<<<2, 128, 0, stream>>>(bsum, nbS);
    k_scan3<<<dim3(nbS, 2), 256, 0, stream>>>(rowptr0, rowptr1, bsum);
    k_self<<<dim3(nbN, 2), 256, 0, stream>>>(rowptr0, rowptr1, deg0, deg1,
                                             eo0, eo1, cur0, cur1, dis0, dis1);
    k_fill<<<dim3(nbE4, 2), 256, 0, stream>>>(ei0, ew0, ei1, ew1,
                                              cur0, cur1, dis0, dis1, eo0, eo1);

    // --- packing ---
    k_packx<<<(NN * 64 + 255) / 256, 256, 0, stream>>>(x, d2an, bufA);
    k_packw<<<768, 256, 0, stream>>>(nodeW1, nodeW2, W1a, W1b, W2a, W2b,
                                     W3a, W3b, W4a, W4b, Wfnode, WfL);

    // --- round 1: P = [x|d2an] @ [nodeW1|nodeW2]^T  (bufA=Xc -> bufB=P) ---
    k_gemm<0><<<gP, 256, 0, stream>>>(bufA, 256, Wfnode, 16, bufB, nullptr, nullptr, 256);
    // layer0 (set0 on x0p): agg -> G(bufA); T = g1@W1a^T+g2@W1b^T
    k_agg<256, 0><<<nbA, 256, 0, stream>>>(bufB, rowptr0, eo0, bufA);
    k_gemm<0><<<gL, 256, 0, stream>>>(bufA, 256, WfL, 8, Tbuf, nullptr, nullptr, 128);
    // layer1 (set1 on x1p): agg -> G(bufA); XM = 0.5relu(T)+0.5relu(g@W2) -> bufB
    k_agg<256, 128><<<nbA, 256, 0, stream>>>(bufB, rowptr1, eo1, bufA);
    k_gemm<1><<<gL, 256, 0, stream>>>(bufA, 256, WfL + 32768, 8, bufB, nullptr, Tbuf, 128);

    // --- round 2 on XM (bufB, stride 128) ---
    k_agg<128, 0><<<nbA, 256, 0, stream>>>(bufB, rowptr0, eo0, bufA);
    k_gemm<0><<<gL, 256, 0, stream>>>(bufA, 256, WfL + 2 * 32768, 8, Tbuf, nullptr, nullptr, 128);
    k_agg<128, 0><<<nbA, 256, 0, stream>>>(bufB, rowptr1, eo1, bufA);
    k_gemm<2><<<gL, 256, 0, stream>>>(bufA, 256, WfL + 3 * 32768, 8, nullptr, out, Tbuf, 128);
}

// Round 4
// 963.510 us; speedup vs baseline: 1.5782x; 1.0804x over previous
//
#include <hip/hip_runtime.h>
#include <hip/hip_fp16.h>
#include <stdint.h>

// Problem constants (from reference)
#define NN 100000      // nodes
#define NE 1600000     // edges per set
#define ETOT (NE + NN) // edges + self loops

typedef __attribute__((ext_vector_type(8))) short bf16x8;
typedef __attribute__((ext_vector_type(4))) float f32x4;
typedef __attribute__((ext_vector_type(4))) unsigned short us4;

__device__ __forceinline__ float bf2f(unsigned short u) {
    union { unsigned int i; float f; } x; x.i = ((unsigned int)u) << 16; return x.f;
}
__device__ __forceinline__ unsigned short f2bf(float f) {
    union { float f; unsigned int i; } x; x.f = f;
    unsigned int i = x.i;
    return (unsigned short)((i + 0x7FFFu + ((i >> 16) & 1u)) >> 16);
}
// pack two fp16 coefficients into one int
__device__ __forceinline__ int packab(float a, float b) {
    unsigned int ua = __half_as_ushort(__float2half_rn(a));
    unsigned int ub = __half_as_ushort(__float2half_rn(b));
    return (int)(ua | (ub << 16));
}
__device__ __forceinline__ float2 unpackab(int p) {
    float a = __half2float(__ushort_as_half((unsigned short)(p & 0xFFFF)));
    float b = __half2float(__ushort_as_half((unsigned short)(((unsigned int)p) >> 16)));
    return make_float2(a, b);
}

// ---------- CSR build (blockIdx.y = edge set for all merged kernels) ----------
__global__ void k_init_deg(int* deg0, int* deg1) {
    int i = blockIdx.x * 256 + threadIdx.x;
    if (i < NN) { deg0[i] = 1; deg1[i] = 1; }   // self-loop included
}

// 4 edges/thread, int4 load, 4 independent atomic chains, both sets in one grid
__global__ void k_count(const int* col0, const int* col1, int* deg0, int* deg1) {
    int t = blockIdx.x * 256 + threadIdx.x;
    if (t * 4 >= NE) return;
    const int* col = blockIdx.y ? col1 : col0;
    int* deg = blockIdx.y ? deg1 : deg0;
    int4 a = ((const int4*)col)[t];
    atomicAdd(&deg[a.x], 1); atomicAdd(&deg[a.y], 1);
    atomicAdd(&deg[a.z], 1); atomicAdd(&deg[a.w], 1);
}

// block scans 1024 elems (4/thread); writes inclusive scan into rowptr[i+1]
__global__ void k_scan1(const int* deg0, const int* deg1, int* rp0, int* rp1s, int* bsum) {
    __shared__ int s[256];
    const int* deg = blockIdx.y ? deg1 : deg0;
    int* rp = (blockIdx.y ? rp1s : rp0) + 1;
    int* bs = bsum + blockIdx.y * 128;
    int tid = threadIdx.x;
    int base = blockIdx.x * 1024 + tid * 4;
    int v0 = 0, v1 = 0, v2 = 0, v3 = 0;
    if (base + 0 < NN) v0 = deg[base + 0];
    if (base + 1 < NN) v1 = deg[base + 1];
    if (base + 2 < NN) v2 = deg[base + 2];
    if (base + 3 < NN) v3 = deg[base + 3];
    int sum = v0 + v1 + v2 + v3;
    s[tid] = sum; __syncthreads();
    for (int off = 1; off < 256; off <<= 1) {
        int t = (tid >= off) ? s[tid - off] : 0;
        __syncthreads(); s[tid] += t; __syncthreads();
    }
    int run = s[tid] - sum;
    if (base + 0 < NN) { run += v0; rp[base + 0] = run; }
    if (base + 1 < NN) { run += v1; rp[base + 1] = run; }
    if (base + 2 < NN) { run += v2; rp[base + 2] = run; }
    if (base + 3 < NN) { run += v3; rp[base + 3] = run; }
    if (tid == 255) bs[blockIdx.x] = s[255];
}

__global__ void k_scan2(int* bsum, int nb) {  // per-block exclusive scan, 2 sets
    __shared__ int s[128];
    int* bs = bsum + blockIdx.x * 128;
    int tid = threadIdx.x;
    int v = (tid < nb) ? bs[tid] : 0;
    s[tid] = v; __syncthreads();
    for (int off = 1; off < 128; off <<= 1) {
        int t = (tid >= off) ? s[tid - off] : 0;
        __syncthreads(); s[tid] += t; __syncthreads();
    }
    if (tid < nb) bs[tid] = s[tid] - v;
}

__global__ void k_scan3(int* rp0, int* rp1s, const int* bsum) {
    int* rowptr = blockIdx.y ? rp1s : rp0;
    int add = bsum[blockIdx.y * 128 + blockIdx.x];
    int tid = threadIdx.x;
    int base = blockIdx.x * 1024 + tid * 4;
    #pragma unroll
    for (int i = 0; i < 4; i++) {
        int idx = base + i;
        if (idx < NN) rowptr[idx + 1] += add;
    }
    if (blockIdx.x == 0 && tid == 0) rowptr[0] = 0;
}

// self-loop in slot rowptr[c] (a = 1/deg = dis^2, b = 1); init cursor + dis
__global__ void k_self(const int* rp0, const int* rp1s, const int* deg0, const int* deg1,
                       int2* eo0, int2* eo1, int* cur0, int* cur1, float* dis0, float* dis1) {
    int i = blockIdx.x * 256 + threadIdx.x;
    if (i >= NN) return;
    const int* rowptr = blockIdx.y ? rp1s : rp0;
    const int* deg = blockIdx.y ? deg1 : deg0;
    int2* eo = blockIdx.y ? eo1 : eo0;
    int* cursor = blockIdx.y ? cur1 : cur0;
    float* dis = blockIdx.y ? dis1 : dis0;
    int p = rowptr[i];
    float d = (float)deg[i];
    eo[p] = make_int2(i, packab(1.0f / d, 1.0f));
    cursor[i] = p + 1;
    dis[i] = rsqrtf(d);
}

// XCD-sliced scatter: consecutive blockIdx.x round-robin across the 8 XCDs,
// so block (chunk, slice=blockIdx.x&7) processes only edges whose destination
// node falls in slice c*8/NN. All writers of any eo cache line then run on one
// XCD, whose 4MB L2 holds the 1.7MB eo slice -> the 8 records of each 64B
// line coalesce in L2 before writeback (was: 1 full line evicted per 8B
// record, 203MB writes). cursor atomics also become XCD-local. The col array
// is read 8x but is L3-resident after the first pass.
__global__ void k_fill(const int* ei0, const float* ew0, const int* ei1, const float* ew1,
                       int* cur0, int* cur1, const float* dis0, const float* dis1,
                       int2* eo0, int2* eo1) {
    int slice = blockIdx.x & 7;
    int e = (blockIdx.x >> 3) * 256 + threadIdx.x;
    if (e >= NE) return;
    const int* er = blockIdx.y ? ei1 : ei0;
    int c = er[NE + e];
    int s = (int)((unsigned long long)(unsigned int)c * 8u / 100000u);
    if (s != slice) return;
    const float* ew = blockIdx.y ? ew1 : ew0;
    int* cursor = blockIdx.y ? cur1 : cur0;
    const float* dis = blockIdx.y ? dis1 : dis0;
    int2* eo = blockIdx.y ? eo1 : eo0;
    int r = er[e];
    float a = dis[r] * dis[c];
    float b = fminf(rsqrtf(ew[e]), 1.0f);
    int p = atomicAdd(&cursor[c], 1);
    eo[p] = make_int2(r, packab(a, b));
}

// ---------- packing ----------
// Xc[N][256] bf16 = [x | d2an | 0-pad]; 4 cols/thread
__global__ void k_packx(const float* x, const float* d2, unsigned short* Xc) {
    int idx = blockIdx.x * 256 + threadIdx.x;   // NN*64 total
    if (idx >= NN * 64) return;
    int r = idx >> 6, k4 = (idx & 63) << 2;
    us4 o;
    if (k4 < 128) {
        float4 v = *(const float4*)(x + (size_t)r * 128 + k4);
        o[0] = f2bf(v.x); o[1] = f2bf(v.y); o[2] = f2bf(v.z); o[3] = f2bf(v.w);
    } else {
        #pragma unroll
        for (int i = 0; i < 4; i++) {
            int k = k4 + i;
            float v = (k < 226) ? d2[(size_t)r * 98 + (k - 128)] : 0.f;
            o[i] = f2bf(v);
        }
    }
    *(us4*)(Xc + (size_t)r * 256 + k4) = o;
}

// All weights packed in one dispatch, MFMA B-fragment order:
// Wf[ks][ct][lane][j] = Worig[c][k], k = ks*32 + (lane>>4)*8 + j, c = ct*16 + (lane&15)
__global__ void k_packw(const float* wn1, const float* wn2,
                        const float* w1a, const float* w1b,
                        const float* w2a, const float* w2b,
                        const float* w3a, const float* w3b,
                        const float* w4a, const float* w4b,
                        unsigned short* Wfnode, unsigned short* WfL) {
    int idx = blockIdx.x * 256 + threadIdx.x;   // 65536 + 4*32768 = 196608
    if (idx < 65536) {
        int j = idx & 7, lane = (idx >> 3) & 63, ct = (idx >> 9) & 15, ks = idx >> 13;
        int k = ks * 32 + (lane >> 4) * 8 + j;
        int c = ct * 16 + (lane & 15);
        float v = 0.f;
        if (k < 226) v = (c < 128) ? wn1[c * 226 + k] : wn2[(c - 128) * 226 + k];
        Wfnode[idx] = f2bf(v);
    } else if (idx < 196608) {
        int li = idx - 65536;
        int set = li >> 15, r = li & 32767;
        const float* wa = (set == 0) ? w1a : (set == 1) ? w2a : (set == 2) ? w3a : w4a;
        const float* wb = (set == 0) ? w1b : (set == 1) ? w2b : (set == 2) ? w3b : w4b;
        int j = r & 7, lane = (r >> 3) & 63, ct = (r >> 9) & 7, ks = r >> 12;
        int k = ks * 32 + (lane >> 4) * 8 + j;
        int c = ct * 16 + (lane & 15);
        float v = (k < 128) ? wa[c * 128 + k] : wb[c * 128 + (k - 128)];
        WfL[li] = f2bf(v);
    }
}

// ---------- aggregation: one wave per node, 16/4/1 ILP tiers ----------
// g1 = sum a_e*S[row_e], g2 = sum b_e*S[row_e]; coefficients in edge record
template <int SRST, int SOFF>
__global__ __launch_bounds__(256) void k_agg(const unsigned short* S,
                                             const int* rowptr, const int2* eg,
                                             unsigned short* G) {
    int c = blockIdx.x * 4 + (threadIdx.x >> 6);
    int lane = threadIdx.x & 63;
    if (c >= NN) return;
    float a0 = 0.f, a1 = 0.f, b0 = 0.f, b1 = 0.f;
    int jb = rowptr[c], je = rowptr[c + 1];
    const unsigned short* Sb = S + SOFF + lane * 2;
    int j = jb;
    for (; j + 16 <= je; j += 16) {
        int2 e[16]; unsigned int u[16];
        #pragma unroll
        for (int i = 0; i < 16; i++) e[i] = eg[j + i];
        #pragma unroll
        for (int i = 0; i < 16; i++)
            u[i] = *(const unsigned int*)(Sb + (size_t)e[i].x * SRST);
        #pragma unroll
        for (int i = 0; i < 16; i++) {
            float2 w = unpackab(e[i].y);
            float x0 = bf2f((unsigned short)(u[i] & 0xFFFF));
            float x1 = bf2f((unsigned short)(u[i] >> 16));
            a0 += w.x * x0; a1 += w.x * x1; b0 += w.y * x0; b1 += w.y * x1;
        }
    }
    for (; j + 4 <= je; j += 4) {
        int2 e[4]; unsigned int u[4];
        #pragma unroll
        for (int i = 0; i < 4; i++) e[i] = eg[j + i];
        #pragma unroll
        for (int i = 0; i < 4; i++)
            u[i] = *(const unsigned int*)(Sb + (size_t)e[i].x * SRST);
        #pragma unroll
        for (int i = 0; i < 4; i++) {
            float2 w = unpackab(e[i].y);
            float x0 = bf2f((unsigned short)(u[i] & 0xFFFF));
            float x1 = bf2f((unsigned short)(u[i] >> 16));
            a0 += w.x * x0; a1 += w.x * x1; b0 += w.y * x0; b1 += w.y * x1;
        }
    }
    for (; j < je; j++) {
        int2 e = eg[j];
        unsigned int u = *(const unsigned int*)(Sb + (size_t)e.x * SRST);
        float2 w = unpackab(e.y);
        float x0 = bf2f((unsigned short)(u & 0xFFFF));
        float x1 = bf2f((unsigned short)(u >> 16));
        a0 += w.x * x0; a1 += w.x * x1; b0 += w.y * x0; b1 += w.y * x1;
    }
    unsigned int* gd = (unsigned int*)(G + (size_t)c * 256);
    gd[lane]      = (unsigned int)f2bf(a0) | ((unsigned int)f2bf(a1) << 16);
    gd[64 + lane] = (unsigned int)f2bf(b0) | ((unsigned int)f2bf(b1) << 16);
}

// ---------- GEMM: C[64 x 128-per-blockIdx.y] = A[N][256] @ Wf, no LDS ----------
// MODE 0: store bf16 plain; 1: store bf16 0.5*relu(T)+0.5*relu(acc); 2: same but f32 to out
template <int MODE>
__global__ __launch_bounds__(256) void k_gemm(const unsigned short* A, int arst,
                                              const unsigned short* Wf, int nct_total,
                                              unsigned short* outB, float* outF,
                                              const unsigned short* T, int orst) {
    int wave = threadIdx.x >> 6, lane = threadIdx.x & 63;
    int m = lane & 15, quad = lane >> 4;
    int row0 = blockIdx.x * 64 + wave * 16;
    int arow = row0 + m;
    bool rowok = arow < NN;
    const unsigned short* Ap = A + (size_t)arow * arst + quad * 8;
    int ctbase = blockIdx.y * 8;
    f32x4 acc[8];
    #pragma unroll
    for (int t = 0; t < 8; t++) acc[t] = (f32x4){0.f, 0.f, 0.f, 0.f};

    #pragma unroll
    for (int ks = 0; ks < 8; ks++) {
        bf16x8 a;
        if (rowok) a = *(const bf16x8*)(Ap + ks * 32);
        else       a = (bf16x8){0, 0, 0, 0, 0, 0, 0, 0};
        const unsigned short* wp = Wf + ((size_t)(ks * nct_total + ctbase) * 64 + lane) * 8;
        #pragma unroll
        for (int t = 0; t < 8; t++) {
            bf16x8 b = *(const bf16x8*)(wp + t * 512);
            acc[t] = __builtin_amdgcn_mfma_f32_16x16x32_bf16(a, b, acc[t], 0, 0, 0);
        }
    }

    int col0 = blockIdx.y * 128;
    #pragma unroll
    for (int t = 0; t < 8; t++) {
        int c = col0 + t * 16 + m;
        #pragma unroll
        for (int rg = 0; rg < 4; rg++) {
            int r = row0 + quad * 4 + rg;
            if (r < NN) {
                float v = acc[t][rg];
                if (MODE == 0) {
                    outB[(size_t)r * orst + c] = f2bf(v);
                } else {
                    float tv = bf2f(T[(size_t)r * 128 + c]);
                    float o = 0.5f * fmaxf(tv, 0.f) + 0.5f * fmaxf(v, 0.f);
                    if (MODE == 1) outB[(size_t)r * orst + c] = f2bf(o);
                    else           outF[(size_t)r * 128 + c] = o;
                }
            }
        }
    }
}

extern "C" void kernel_launch(void* const* d_in, const int* in_sizes, int n_in,
                              void* d_out, int out_size, void* d_ws, size_t ws_size,
                              hipStream_t stream) {
    const float* x      = (const float*)d_in[0];
    const float* d2an   = (const float*)d_in[1];
    const int*   ei0    = (const int*)d_in[2];
    const float* ew0    = (const float*)d_in[3];
    const int*   ei1    = (const int*)d_in[4];
    const float* ew1    = (const float*)d_in[5];
    const float* nodeW1 = (const float*)d_in[6];
    const float* nodeW2 = (const float*)d_in[7];
    const float* W1a = (const float*)d_in[8],  *W1b = (const float*)d_in[9];
    const float* W2a = (const float*)d_in[10], *W2b = (const float*)d_in[11];
    const float* W3a = (const float*)d_in[12], *W3b = (const float*)d_in[13];
    const float* W4a = (const float*)d_in[14], *W4b = (const float*)d_in[15];
    float* out = (float*)d_out;

    // ws carve-out
    char* p = (char*)d_ws;
    auto alloc = [&](size_t bytes) -> char* {
        char* r = p; p += (bytes + 255) & ~(size_t)255; return r;
    };
    unsigned short* bufA   = (unsigned short*)alloc((size_t)NN * 256 * 2); // Xc -> G
    unsigned short* bufB   = (unsigned short*)alloc((size_t)NN * 256 * 2); // P  -> XM
    unsigned short* Tbuf   = (unsigned short*)alloc((size_t)NN * 128 * 2);
    unsigned short* Wfnode = (unsigned short*)alloc(65536 * 2);
    unsigned short* WfL    = (unsigned short*)alloc((size_t)4 * 32768 * 2);
    int*    deg0    = (int*)alloc((size_t)NN * 4);
    int*    deg1    = (int*)alloc((size_t)NN * 4);
    int*    rowptr0 = (int*)alloc((size_t)(NN + 1) * 4);
    int*    rowptr1 = (int*)alloc((size_t)(NN + 1) * 4);
    int*    cur0    = (int*)alloc((size_t)NN * 4);
    int*    cur1    = (int*)alloc((size_t)NN * 4);
    int*    bsum    = (int*)alloc(2 * 128 * 4);
    float*  dis0    = (float*)alloc((size_t)NN * 4);
    float*  dis1    = (float*)alloc((size_t)NN * 4);
    int2*   eo0     = (int2*)alloc((size_t)ETOT * 8);
    int2*   eo1     = (int2*)alloc((size_t)ETOT * 8);

    int nbN  = (NN + 255) / 256;
    int nbE1 = (NE + 255) / 256;          // 1 edge/thread
    int nbE4 = (NE / 4 + 255) / 256;      // 4 edges/thread
    int nbS  = (NN + 1023) / 1024;        // 98 scan blocks
    dim3 gP((NN + 63) / 64, 2);           // P gemm: 256 output cols
    dim3 gL((NN + 63) / 64, 1);           // layer gemms: 128 output cols
    int nbA = (NN + 3) / 4;               // agg: 4 waves/block, 1 wave/node

    // --- CSR build, both sets per dispatch (blockIdx.y = set) ---
    k_init_deg<<<nbN, 256, 0, stream>>>(deg0, deg1);
    k_count<<<dim3(nbE4, 2), 256, 0, stream>>>(ei0 + NE, ei1 + NE, deg0, deg1);
    k_scan1<<<dim3(nbS, 2), 256, 0, stream>>>(deg0, deg1, rowptr0, rowptr1, bsum);
    k_scan2<<<2, 128, 0, stream>>>(bsum, nbS);
    k_scan3<<<dim3(nbS, 2), 256, 0, stream>>>(rowptr0, rowptr1, bsum);
    k_self<<<dim3(nbN, 2), 256, 0, stream>>>(rowptr0, rowptr1, deg0, deg1,
                                             eo0, eo1, cur0, cur1, dis0, dis1);
    // 8 slice-replicas per edge chunk; slice = blockIdx.x & 7 (XCD round-robin)
    k_fill<<<dim3(nbE1 * 8, 2), 256, 0, stream>>>(ei0, ew0, ei1, ew1,
                                                  cur0, cur1, dis0, dis1, eo0, eo1);

    // --- packing ---
    k_packx<<<(NN * 64 + 255) / 256, 256, 0, stream>>>(x, d2an, bufA);
    k_packw<<<768, 256, 0, stream>>>(nodeW1, nodeW2, W1a, W1b, W2a, W2b,
                                     W3a, W3b, W4a, W4b, Wfnode, WfL);

    // --- round 1: P = [x|d2an] @ [nodeW1|nodeW2]^T  (bufA=Xc -> bufB=P) ---
    k_gemm<0><<<gP, 256, 0, stream>>>(bufA, 256, Wfnode, 16, bufB, nullptr, nullptr, 256);
    // layer0 (set0 on x0p): agg -> G(bufA); T = g1@W1a^T+g2@W1b^T
    k_agg<256, 0><<<nbA, 256, 0, stream>>>(bufB, rowptr0, eo0, bufA);
    k_gemm<0><<<gL, 256, 0, stream>>>(bufA, 256, WfL, 8, Tbuf, nullptr, nullptr, 128);
    // layer1 (set1 on x1p): agg -> G(bufA); XM = 0.5relu(T)+0.5relu(g@W2) -> bufB
    k_agg<256, 128><<<nbA, 256, 0, stream>>>(bufB, rowptr1, eo1, bufA);
    k_gemm<1><<<gL, 256, 0, stream>>>(bufA, 256, WfL + 32768, 8, bufB, nullptr, Tbuf, 128);

    // --- round 2 on XM (bufB, stride 128) ---
    k_agg<128, 0><<<nbA, 256, 0, stream>>>(bufB, rowptr0, eo0, bufA);
    k_gemm<0><<<gL, 256, 0, stream>>>(bufA, 256, WfL + 2 * 32768, 8, Tbuf, nullptr, nullptr, 128);
    k_agg<128, 0><<<nbA, 256, 0, stream>>>(bufB, rowptr1, eo1, bufA);
    k_gemm<2><<<gL, 256, 0, stream>>>(bufA, 256, WfL + 3 * 32768, 8, nullptr, out, Tbuf, 128);
}

// Round 5
// 916.429 us; speedup vs baseline: 1.6592x; 1.0514x over previous
//
#include <hip/hip_runtime.h>
#include <hip/hip_fp16.h>
#include <stdint.h>

// Problem constants (from reference)
#define NN 100000      // nodes
#define NE 1600000     // edges per set
#define ETOT (NE + NN) // edges + self loops
#define EPB 8192                      // edges per block in bucket passes
#define NBLK ((NE + EPB - 1) / EPB)   // 196 chunk blocks
#define NPB 512                       // nodes per bucket (c >> 9)
#define NBUK ((NN + NPB - 1) / NPB)   // 196 buckets

typedef __attribute__((ext_vector_type(8))) short bf16x8;
typedef __attribute__((ext_vector_type(4))) float f32x4;
typedef __attribute__((ext_vector_type(4))) unsigned short us4;

__device__ __forceinline__ float bf2f(unsigned short u) {
    union { unsigned int i; float f; } x; x.i = ((unsigned int)u) << 16; return x.f;
}
__device__ __forceinline__ unsigned short f2bf(float f) {
    union { float f; unsigned int i; } x; x.f = f;
    unsigned int i = x.i;
    return (unsigned short)((i + 0x7FFFu + ((i >> 16) & 1u)) >> 16);
}
// pack two fp16 coefficients into one int
__device__ __forceinline__ int packab(float a, float b) {
    unsigned int ua = __half_as_ushort(__float2half_rn(a));
    unsigned int ub = __half_as_ushort(__float2half_rn(b));
    return (int)(ua | (ub << 16));
}
__device__ __forceinline__ float2 unpackab(int p) {
    float a = __half2float(__ushort_as_half((unsigned short)(p & 0xFFFF)));
    float b = __half2float(__ushort_as_half((unsigned short)(((unsigned int)p) >> 16)));
    return make_float2(a, b);
}

// ---------- CSR build (blockIdx.y = edge set for all merged kernels) ----------
__global__ void k_init_deg(int* deg0, int* deg1) {
    int i = blockIdx.x * 256 + threadIdx.x;
    if (i < NN) { deg0[i] = 1; deg1[i] = 1; }   // self-loop included
}

// 4 edges/thread, int4 load, 4 independent atomic chains, both sets in one grid
__global__ void k_count(const int* col0, const int* col1, int* deg0, int* deg1) {
    int t = blockIdx.x * 256 + threadIdx.x;
    if (t * 4 >= NE) return;
    const int* col = blockIdx.y ? col1 : col0;
    int* deg = blockIdx.y ? deg1 : deg0;
    int4 a = ((const int4*)col)[t];
    atomicAdd(&deg[a.x], 1); atomicAdd(&deg[a.y], 1);
    atomicAdd(&deg[a.z], 1); atomicAdd(&deg[a.w], 1);
}

// block scans 1024 elems (4/thread); writes inclusive scan into rowptr[i+1]
__global__ void k_scan1(const int* deg0, const int* deg1, int* rp0, int* rp1s, int* bsum) {
    __shared__ int s[256];
    const int* deg = blockIdx.y ? deg1 : deg0;
    int* rp = (blockIdx.y ? rp1s : rp0) + 1;
    int* bs = bsum + blockIdx.y * 128;
    int tid = threadIdx.x;
    int base = blockIdx.x * 1024 + tid * 4;
    int v0 = 0, v1 = 0, v2 = 0, v3 = 0;
    if (base + 0 < NN) v0 = deg[base + 0];
    if (base + 1 < NN) v1 = deg[base + 1];
    if (base + 2 < NN) v2 = deg[base + 2];
    if (base + 3 < NN) v3 = deg[base + 3];
    int sum = v0 + v1 + v2 + v3;
    s[tid] = sum; __syncthreads();
    for (int off = 1; off < 256; off <<= 1) {
        int t = (tid >= off) ? s[tid - off] : 0;
        __syncthreads(); s[tid] += t; __syncthreads();
    }
    int run = s[tid] - sum;
    if (base + 0 < NN) { run += v0; rp[base + 0] = run; }
    if (base + 1 < NN) { run += v1; rp[base + 1] = run; }
    if (base + 2 < NN) { run += v2; rp[base + 2] = run; }
    if (base + 3 < NN) { run += v3; rp[base + 3] = run; }
    if (tid == 255) bs[blockIdx.x] = s[255];
}

__global__ void k_scan2(int* bsum, int nb) {  // per-block exclusive scan, 2 sets
    __shared__ int s[128];
    int* bs = bsum + blockIdx.x * 128;
    int tid = threadIdx.x;
    int v = (tid < nb) ? bs[tid] : 0;
    s[tid] = v; __syncthreads();
    for (int off = 1; off < 128; off <<= 1) {
        int t = (tid >= off) ? s[tid - off] : 0;
        __syncthreads(); s[tid] += t; __syncthreads();
    }
    if (tid < nb) bs[tid] = s[tid] - v;
}

__global__ void k_scan3(int* rp0, int* rp1s, const int* bsum) {
    int* rowptr = blockIdx.y ? rp1s : rp0;
    int add = bsum[blockIdx.y * 128 + blockIdx.x];
    int tid = threadIdx.x;
    int base = blockIdx.x * 1024 + tid * 4;
    #pragma unroll
    for (int i = 0; i < 4; i++) {
        int idx = base + i;
        if (idx < NN) rowptr[idx + 1] += add;
    }
    if (blockIdx.x == 0 && tid == 0) rowptr[0] = 0;
}

// self-loop in slot rowptr[c] (a = 1/deg = dis^2, b = 1); init dis
__global__ void k_self(const int* rp0, const int* rp1s, const int* deg0, const int* deg1,
                       int2* eo0, int2* eo1, float* dis0, float* dis1) {
    int i = blockIdx.x * 256 + threadIdx.x;
    if (i >= NN) return;
    const int* rowptr = blockIdx.y ? rp1s : rp0;
    const int* deg = blockIdx.y ? deg1 : deg0;
    int2* eo = blockIdx.y ? eo1 : eo0;
    float* dis = blockIdx.y ? dis1 : dis0;
    int p = rowptr[i];
    float d = (float)deg[i];
    eo[p] = make_int2(i, packab(1.0f / d, 1.0f));
    dis[i] = rsqrtf(d);
}

// ---- bucket sort pass A1: per-(chunk-block, bucket) histogram, LDS only ----
__global__ __launch_bounds__(256) void k_cnt(const int* ei0, const int* ei1, int* cntm) {
    __shared__ int h[NBUK];
    const int* col = (blockIdx.y ? ei1 : ei0) + NE;
    for (int i = threadIdx.x; i < NBUK; i += 256) h[i] = 0;
    __syncthreads();
    int base = blockIdx.x * EPB;
    for (int i = 0; i < EPB / 256; i++) {
        int e = base + i * 256 + threadIdx.x;
        if (e < NE) atomicAdd(&h[col[e] >> 9], 1);
    }
    __syncthreads();
    int* out = cntm + ((size_t)blockIdx.y * NBLK + blockIdx.x) * NBUK;
    for (int i = threadIdx.x; i < NBUK; i += 256) out[i] = h[i];
}

// ---- pass A2: per-bucket exclusive scan over chunk blocks -> staging bases ----
// stage slab for bucket b starts at rowptr[b*NPB] (capacity includes self-loop
// slots, so records always fit). btot[b] = total records in bucket.
__global__ __launch_bounds__(256) void k_base(const int* rp0, const int* rp1s,
                                              const int* cntm, int* basem, int* btot) {
    __shared__ int s[256];
    int b = blockIdx.x;
    const int* rowptr = blockIdx.y ? rp1s : rp0;
    const int* cnt = cntm + (size_t)blockIdx.y * NBLK * NBUK;
    int t = threadIdx.x;
    int v = (t < NBLK) ? cnt[(size_t)t * NBUK + b] : 0;
    s[t] = v; __syncthreads();
    for (int off = 1; off < 256; off <<= 1) {
        int u = (t >= off) ? s[t - off] : 0;
        __syncthreads(); s[t] += u; __syncthreads();
    }
    int excl = s[t] - v;
    int base0 = rowptr[b * NPB];
    if (t < NBLK) basem[((size_t)blockIdx.y * NBLK + t) * NBUK + b] = base0 + excl;
    if (t == 255) btot[blockIdx.y * NBUK + b] = s[255];
}

// ---- pass A3: scatter records into per-(block,bucket) contiguous staging runs.
// All writers of a staging cache line are threads of ONE block writing within a
// short window -> lines merge in that CU's L2 (the fix for the 8x write
// amplification: temporal locality, not XCD locality — R4 lesson).
// record: x = r | (c&511)<<17 (r<2^17), y = packab(a,b)
__global__ __launch_bounds__(256) void k_scat1(const int* ei0, const float* ew0,
                                               const int* ei1, const float* ew1,
                                               const float* dis0, const float* dis1,
                                               const int* basem, int2* st0, int2* st1) {
    __shared__ int lb[NBUK];
    __shared__ int lc[NBUK];
    const int* er = blockIdx.y ? ei1 : ei0;
    const float* ew = blockIdx.y ? ew1 : ew0;
    const float* dis = blockIdx.y ? dis1 : dis0;
    int2* st = blockIdx.y ? st1 : st0;
    const int* bm = basem + ((size_t)blockIdx.y * NBLK + blockIdx.x) * NBUK;
    for (int i = threadIdx.x; i < NBUK; i += 256) { lb[i] = bm[i]; lc[i] = 0; }
    __syncthreads();
    int base = blockIdx.x * EPB;
    for (int i = 0; i < EPB / 256; i++) {
        int e = base + i * 256 + threadIdx.x;
        if (e >= NE) break;             // e monotone in i -> safe early exit
        int r = er[e];
        int c = er[NE + e];
        int bkt = c >> 9;
        int rank = atomicAdd(&lc[bkt], 1);
        float a = dis[r] * dis[c];
        float b = fminf(rsqrtf(ew[e]), 1.0f);
        st[lb[bkt] + rank] = make_int2(r | ((c & 511) << 17), packab(a, b));
    }
}

// ---- pass B: one block per bucket; coalesced read of the bucket's staged
// slab; exact positions via LDS counters; scatter confined to the bucket's
// ~73KB eo window by one block in a tight time window -> L2 merges lines.
__global__ __launch_bounds__(256) void k_scat2(const int* rp0, const int* rp1s,
                                               const int* btot,
                                               const int2* st0, const int2* st1,
                                               int2* eo0, int2* eo1) {
    __shared__ int lcur[NPB];
    int b = blockIdx.x;
    const int* rowptr = blockIdx.y ? rp1s : rp0;
    const int2* st = blockIdx.y ? st1 : st0;
    int2* eo = blockIdx.y ? eo1 : eo0;
    int nstart = b * NPB;
    for (int i = threadIdx.x; i < NPB; i += 256) {
        int node = nstart + i;
        if (node < NN) lcur[i] = rowptr[node] + 1;   // +1: self-loop slot
    }
    __syncthreads();
    int s0 = rowptr[nstart];
    int tot = btot[blockIdx.y * NBUK + b];
    for (int j = s0 + (int)threadIdx.x; j < s0 + tot; j += 256) {
        int2 rec = st[j];
        int cl = (rec.x >> 17) & 511;
        int pos = atomicAdd(&lcur[cl], 1);
        eo[pos] = make_int2(rec.x & 0x1FFFF, rec.y);
    }
}

// ---------- packing ----------
// Xc[N][256] bf16 = [x | d2an | 0-pad]; 4 cols/thread
__global__ void k_packx(const float* x, const float* d2, unsigned short* Xc) {
    int idx = blockIdx.x * 256 + threadIdx.x;   // NN*64 total
    if (idx >= NN * 64) return;
    int r = idx >> 6, k4 = (idx & 63) << 2;
    us4 o;
    if (k4 < 128) {
        float4 v = *(const float4*)(x + (size_t)r * 128 + k4);
        o[0] = f2bf(v.x); o[1] = f2bf(v.y); o[2] = f2bf(v.z); o[3] = f2bf(v.w);
    } else {
        #pragma unroll
        for (int i = 0; i < 4; i++) {
            int k = k4 + i;
            float v = (k < 226) ? d2[(size_t)r * 98 + (k - 128)] : 0.f;
            o[i] = f2bf(v);
        }
    }
    *(us4*)(Xc + (size_t)r * 256 + k4) = o;
}

// All weights packed in one dispatch, MFMA B-fragment order:
// Wf[ks][ct][lane][j] = Worig[c][k], k = ks*32 + (lane>>4)*8 + j, c = ct*16 + (lane&15)
__global__ void k_packw(const float* wn1, const float* wn2,
                        const float* w1a, const float* w1b,
                        const float* w2a, const float* w2b,
                        const float* w3a, const float* w3b,
                        const float* w4a, const float* w4b,
                        unsigned short* Wfnode, unsigned short* WfL) {
    int idx = blockIdx.x * 256 + threadIdx.x;   // 65536 + 4*32768 = 196608
    if (idx < 65536) {
        int j = idx & 7, lane = (idx >> 3) & 63, ct = (idx >> 9) & 15, ks = idx >> 13;
        int k = ks * 32 + (lane >> 4) * 8 + j;
        int c = ct * 16 + (lane & 15);
        float v = 0.f;
        if (k < 226) v = (c < 128) ? wn1[c * 226 + k] : wn2[(c - 128) * 226 + k];
        Wfnode[idx] = f2bf(v);
    } else if (idx < 196608) {
        int li = idx - 65536;
        int set = li >> 15, r = li & 32767;
        const float* wa = (set == 0) ? w1a : (set == 1) ? w2a : (set == 2) ? w3a : w4a;
        const float* wb = (set == 0) ? w1b : (set == 1) ? w2b : (set == 2) ? w3b : w4b;
        int j = r & 7, lane = (r >> 3) & 63, ct = (r >> 9) & 7, ks = r >> 12;
        int k = ks * 32 + (lane >> 4) * 8 + j;
        int c = ct * 16 + (lane & 15);
        float v = (k < 128) ? wa[c * 128 + k] : wb[c * 128 + (k - 128)];
        WfL[li] = f2bf(v);
    }
}

// ---------- aggregation: one wave per node, 16/4/1 ILP tiers ----------
// g1 = sum a_e*S[row_e], g2 = sum b_e*S[row_e]; coefficients in edge record
template <int SRST, int SOFF>
__global__ __launch_bounds__(256) void k_agg(const unsigned short* S,
                                             const int* rowptr, const int2* eg,
                                             unsigned short* G) {
    int c = blockIdx.x * 4 + (threadIdx.x >> 6);
    int lane = threadIdx.x & 63;
    if (c >= NN) return;
    float a0 = 0.f, a1 = 0.f, b0 = 0.f, b1 = 0.f;
    int jb = rowptr[c], je = rowptr[c + 1];
    const unsigned short* Sb = S + SOFF + lane * 2;
    int j = jb;
    for (; j + 16 <= je; j += 16) {
        int2 e[16]; unsigned int u[16];
        #pragma unroll
        for (int i = 0; i < 16; i++) e[i] = eg[j + i];
        #pragma unroll
        for (int i = 0; i < 16; i++)
            u[i] = *(const unsigned int*)(Sb + (size_t)e[i].x * SRST);
        #pragma unroll
        for (int i = 0; i < 16; i++) {
            float2 w = unpackab(e[i].y);
            float x0 = bf2f((unsigned short)(u[i] & 0xFFFF));
            float x1 = bf2f((unsigned short)(u[i] >> 16));
            a0 += w.x * x0; a1 += w.x * x1; b0 += w.y * x0; b1 += w.y * x1;
        }
    }
    for (; j + 4 <= je; j += 4) {
        int2 e[4]; unsigned int u[4];
        #pragma unroll
        for (int i = 0; i < 4; i++) e[i] = eg[j + i];
        #pragma unroll
        for (int i = 0; i < 4; i++)
            u[i] = *(const unsigned int*)(Sb + (size_t)e[i].x * SRST);
        #pragma unroll
        for (int i = 0; i < 4; i++) {
            float2 w = unpackab(e[i].y);
            float x0 = bf2f((unsigned short)(u[i] & 0xFFFF));
            float x1 = bf2f((unsigned short)(u[i] >> 16));
            a0 += w.x * x0; a1 += w.x * x1; b0 += w.y * x0; b1 += w.y * x1;
        }
    }
    for (; j < je; j++) {
        int2 e = eg[j];
        unsigned int u = *(const unsigned int*)(Sb + (size_t)e.x * SRST);
        float2 w = unpackab(e.y);
        float x0 = bf2f((unsigned short)(u & 0xFFFF));
        float x1 = bf2f((unsigned short)(u >> 16));
        a0 += w.x * x0; a1 += w.x * x1; b0 += w.y * x0; b1 += w.y * x1;
    }
    unsigned int* gd = (unsigned int*)(G + (size_t)c * 256);
    gd[lane]      = (unsigned int)f2bf(a0) | ((unsigned int)f2bf(a1) << 16);
    gd[64 + lane] = (unsigned int)f2bf(b0) | ((unsigned int)f2bf(b1) << 16);
}

// ---------- GEMM: C[64 x 128-per-blockIdx.y] = A[N][256] @ Wf, no LDS ----------
// MODE 0: store bf16 plain; 1: store bf16 0.5*relu(T)+0.5*relu(acc); 2: same but f32 to out
template <int MODE>
__global__ __launch_bounds__(256) void k_gemm(const unsigned short* A, int arst,
                                              const unsigned short* Wf, int nct_total,
                                              unsigned short* outB, float* outF,
                                              const unsigned short* T, int orst) {
    int wave = threadIdx.x >> 6, lane = threadIdx.x & 63;
    int m = lane & 15, quad = lane >> 4;
    int row0 = blockIdx.x * 64 + wave * 16;
    int arow = row0 + m;
    bool rowok = arow < NN;
    const unsigned short* Ap = A + (size_t)arow * arst + quad * 8;
    int ctbase = blockIdx.y * 8;
    f32x4 acc[8];
    #pragma unroll
    for (int t = 0; t < 8; t++) acc[t] = (f32x4){0.f, 0.f, 0.f, 0.f};

    #pragma unroll
    for (int ks = 0; ks < 8; ks++) {
        bf16x8 a;
        if (rowok) a = *(const bf16x8*)(Ap + ks * 32);
        else       a = (bf16x8){0, 0, 0, 0, 0, 0, 0, 0};
        const unsigned short* wp = Wf + ((size_t)(ks * nct_total + ctbase) * 64 + lane) * 8;
        #pragma unroll
        for (int t = 0; t < 8; t++) {
            bf16x8 b = *(const bf16x8*)(wp + t * 512);
            acc[t] = __builtin_amdgcn_mfma_f32_16x16x32_bf16(a, b, acc[t], 0, 0, 0);
        }
    }

    int col0 = blockIdx.y * 128;
    #pragma unroll
    for (int t = 0; t < 8; t++) {
        int c = col0 + t * 16 + m;
        #pragma unroll
        for (int rg = 0; rg < 4; rg++) {
            int r = row0 + quad * 4 + rg;
            if (r < NN) {
                float v = acc[t][rg];
                if (MODE == 0) {
                    outB[(size_t)r * orst + c] = f2bf(v);
                } else {
                    float tv = bf2f(T[(size_t)r * 128 + c]);
                    float o = 0.5f * fmaxf(tv, 0.f) + 0.5f * fmaxf(v, 0.f);
                    if (MODE == 1) outB[(size_t)r * orst + c] = f2bf(o);
                    else           outF[(size_t)r * 128 + c] = o;
                }
            }
        }
    }
}

extern "C" void kernel_launch(void* const* d_in, const int* in_sizes, int n_in,
                              void* d_out, int out_size, void* d_ws, size_t ws_size,
                              hipStream_t stream) {
    const float* x      = (const float*)d_in[0];
    const float* d2an   = (const float*)d_in[1];
    const int*   ei0    = (const int*)d_in[2];
    const float* ew0    = (const float*)d_in[3];
    const int*   ei1    = (const int*)d_in[4];
    const float* ew1    = (const float*)d_in[5];
    const float* nodeW1 = (const float*)d_in[6];
    const float* nodeW2 = (const float*)d_in[7];
    const float* W1a = (const float*)d_in[8],  *W1b = (const float*)d_in[9];
    const float* W2a = (const float*)d_in[10], *W2b = (const float*)d_in[11];
    const float* W3a = (const float*)d_in[12], *W3b = (const float*)d_in[13];
    const float* W4a = (const float*)d_in[14], *W4b = (const float*)d_in[15];
    float* out = (float*)d_out;

    // ws carve-out
    char* p = (char*)d_ws;
    auto alloc = [&](size_t bytes) -> char* {
        char* r = p; p += (bytes + 255) & ~(size_t)255; return r;
    };
    unsigned short* bufA   = (unsigned short*)alloc((size_t)NN * 256 * 2); // Xc -> G
    unsigned short* bufB   = (unsigned short*)alloc((size_t)NN * 256 * 2); // stage -> P -> XM
    unsigned short* Tbuf   = (unsigned short*)alloc((size_t)NN * 128 * 2);
    unsigned short* Wfnode = (unsigned short*)alloc(65536 * 2);
    unsigned short* WfL    = (unsigned short*)alloc((size_t)4 * 32768 * 2);
    int*    deg0    = (int*)alloc((size_t)NN * 4);
    int*    deg1    = (int*)alloc((size_t)NN * 4);
    int*    rowptr0 = (int*)alloc((size_t)(NN + 1) * 4);
    int*    rowptr1 = (int*)alloc((size_t)(NN + 1) * 4);
    int*    bsum    = (int*)alloc(2 * 128 * 4);
    float*  dis0    = (float*)alloc((size_t)NN * 4);
    float*  dis1    = (float*)alloc((size_t)NN * 4);
    int2*   eo0     = (int2*)alloc((size_t)ETOT * 8);
    int2*   eo1     = (int2*)alloc((size_t)ETOT * 8);
    int*    cntm    = (int*)alloc((size_t)2 * NBLK * NBUK * 4);
    int*    basem   = (int*)alloc((size_t)2 * NBLK * NBUK * 4);
    int*    btot    = (int*)alloc((size_t)2 * NBUK * 4);

    // staging slabs alias bufB (27.2MB <= 51.2MB); bufB's first real use
    // (k_gemm<0> writing P) is stream-ordered after k_scat2 consumes staging.
    int2* st0 = (int2*)bufB;
    int2* st1 = st0 + ETOT;

    int nbN  = (NN + 255) / 256;
    int nbE4 = (NE / 4 + 255) / 256;      // 4 edges/thread
    int nbS  = (NN + 1023) / 1024;        // 98 scan blocks
    dim3 gP((NN + 63) / 64, 2);           // P gemm: 256 output cols
    dim3 gL((NN + 63) / 64, 1);           // layer gemms: 128 output cols
    int nbA = (NN + 3) / 4;               // agg: 4 waves/block, 1 wave/node

    // --- CSR build, both sets per dispatch (blockIdx.y = set) ---
    k_init_deg<<<nbN, 256, 0, stream>>>(deg0, deg1);
    k_count<<<dim3(nbE4, 2), 256, 0, stream>>>(ei0 + NE, ei1 + NE, deg0, deg1);
    k_scan1<<<dim3(nbS, 2), 256, 0, stream>>>(deg0, deg1, rowptr0, rowptr1, bsum);
    k_scan2<<<2, 128, 0, stream>>>(bsum, nbS);
    k_scan3<<<dim3(nbS, 2), 256, 0, stream>>>(rowptr0, rowptr1, bsum);
    k_self<<<dim3(nbN, 2), 256, 0, stream>>>(rowptr0, rowptr1, deg0, deg1,
                                             eo0, eo1, dis0, dis1);
    // --- bucket sort replacing direct scatter (R0 k_fill: 190us, 8x write amp) ---
    k_cnt<<<dim3(NBLK, 2), 256, 0, stream>>>(ei0, ei1, cntm);
    k_base<<<dim3(NBUK, 2), 256, 0, stream>>>(rowptr0, rowptr1, cntm, basem, btot);
    k_scat1<<<dim3(NBLK, 2), 256, 0, stream>>>(ei0, ew0, ei1, ew1,
                                               dis0, dis1, basem, st0, st1);
    k_scat2<<<dim3(NBUK, 2), 256, 0, stream>>>(rowptr0, rowptr1, btot,
                                               st0, st1, eo0, eo1);

    // --- packing ---
    k_packx<<<(NN * 64 + 255) / 256, 256, 0, stream>>>(x, d2an, bufA);
    k_packw<<<768, 256, 0, stream>>>(nodeW1, nodeW2, W1a, W1b, W2a, W2b,
                                     W3a, W3b, W4a, W4b, Wfnode, WfL);

    // --- round 1: P = [x|d2an] @ [nodeW1|nodeW2]^T  (bufA=Xc -> bufB=P) ---
    k_gemm<0><<<gP, 256, 0, stream>>>(bufA, 256, Wfnode, 16, bufB, nullptr, nullptr, 256);
    // layer0 (set0 on x0p): agg -> G(bufA); T = g1@W1a^T+g2@W1b^T
    k_agg<256, 0><<<nbA, 256, 0, stream>>>(bufB, rowptr0, eo0, bufA);
    k_gemm<0><<<gL, 256, 0, stream>>>(bufA, 256, WfL, 8, Tbuf, nullptr, nullptr, 128);
    // layer1 (set1 on x1p): agg -> G(bufA); XM = 0.5relu(T)+0.5relu(g@W2) -> bufB
    k_agg<256, 128><<<nbA, 256, 0, stream>>>(bufB, rowptr1, eo1, bufA);
    k_gemm<1><<<gL, 256, 0, stream>>>(bufA, 256, WfL + 32768, 8, bufB, nullptr, Tbuf, 128);

    // --- round 2 on XM (bufB, stride 128) ---
    k_agg<128, 0><<<nbA, 256, 0, stream>>>(bufB, rowptr0, eo0, bufA);
    k_gemm<0><<<gL, 256, 0, stream>>>(bufA, 256, WfL + 2 * 32768, 8, Tbuf, nullptr, nullptr, 128);
    k_agg<128, 0><<<nbA, 256, 0, stream>>>(bufB, rowptr1, eo1, bufA);
    k_gemm<2><<<gL, 256, 0, stream>>>(bufA, 256, WfL + 3 * 32768, 8, nullptr, out, Tbuf, 128);
}

// Round 6
// 775.352 us; speedup vs baseline: 1.9611x; 1.1820x over previous
//
#include <hip/hip_runtime.h>
#include <hip/hip_fp16.h>
#include <stdint.h>

// Problem constants (from reference)
#define NN 100000      // nodes
#define NE 1600000     // edges per set
#define ETOT (NE + NN) // edges + self loops
#define EPB 8192                      // edges per block in bucket passes
#define NBLK ((NE + EPB - 1) / EPB)   // 196 chunk blocks
#define NPB 512                       // nodes per bucket (c >> 9)
#define NBUK ((NN + NPB - 1) / NPB)   // 196 buckets

typedef __attribute__((ext_vector_type(8))) short bf16x8;
typedef __attribute__((ext_vector_type(4))) float f32x4;
typedef __attribute__((ext_vector_type(4))) unsigned short us4;

__device__ __forceinline__ float bf2f(unsigned short u) {
    union { unsigned int i; float f; } x; x.i = ((unsigned int)u) << 16; return x.f;
}
__device__ __forceinline__ unsigned short f2bf(float f) {
    union { float f; unsigned int i; } x; x.f = f;
    unsigned int i = x.i;
    return (unsigned short)((i + 0x7FFFu + ((i >> 16) & 1u)) >> 16);
}
// pack two fp16 coefficients into one int
__device__ __forceinline__ int packab(float a, float b) {
    unsigned int ua = __half_as_ushort(__float2half_rn(a));
    unsigned int ub = __half_as_ushort(__float2half_rn(b));
    return (int)(ua | (ub << 16));
}
__device__ __forceinline__ float2 unpackab(int p) {
    float a = __half2float(__ushort_as_half((unsigned short)(p & 0xFFFF)));
    float b = __half2float(__ushort_as_half((unsigned short)(((unsigned int)p) >> 16)));
    return make_float2(a, b);
}

// ---------- bucket sort (blockIdx.y = edge set everywhere) ----------
// pass A1: per-(chunk-block, bucket) histogram, LDS only
__global__ __launch_bounds__(256) void k_cnt(const int* ei0, const int* ei1, int* cntm) {
    __shared__ int h[NBUK];
    const int* col = (blockIdx.y ? ei1 : ei0) + NE;
    for (int i = threadIdx.x; i < NBUK; i += 256) h[i] = 0;
    __syncthreads();
    int base = blockIdx.x * EPB;
    for (int i = 0; i < EPB / 256; i++) {
        int e = base + i * 256 + threadIdx.x;
        if (e < NE) atomicAdd(&h[col[e] >> 9], 1);
    }
    __syncthreads();
    int* out = cntm + ((size_t)blockIdx.y * NBLK + blockIdx.x) * NBUK;
    for (int i = threadIdx.x; i < NBUK; i += 256) out[i] = h[i];
}

// pass A2a: bucket totals + exclusive scan -> dense stage-slab offsets
__global__ __launch_bounds__(256) void k_btot(const int* cntm, int* bstart, int* btot) {
    __shared__ int s[256];
    int t = threadIdx.x;
    const int* cnt = cntm + (size_t)blockIdx.y * NBLK * NBUK;
    int tot = 0;
    if (t < NBUK)
        for (int blk = 0; blk < NBLK; blk++) tot += cnt[(size_t)blk * NBUK + t];
    s[t] = tot; __syncthreads();
    for (int off = 1; off < 256; off <<= 1) {
        int u = (t >= off) ? s[t - off] : 0;
        __syncthreads(); s[t] += u; __syncthreads();
    }
    if (t < NBUK) {
        bstart[blockIdx.y * NBUK + t] = s[t] - tot;   // exclusive
        btot[blockIdx.y * NBUK + t] = tot;
    }
}

// pass A2b: per-bucket exclusive scan over chunk blocks -> per-(block,bucket) bases
__global__ __launch_bounds__(256) void k_base2(const int* cntm, const int* bstart, int* basem) {
    __shared__ int s[256];
    int b = blockIdx.x;
    const int* cnt = cntm + (size_t)blockIdx.y * NBLK * NBUK;
    int t = threadIdx.x;
    int v = (t < NBLK) ? cnt[(size_t)t * NBUK + b] : 0;
    s[t] = v; __syncthreads();
    for (int off = 1; off < 256; off <<= 1) {
        int u = (t >= off) ? s[t - off] : 0;
        __syncthreads(); s[t] += u; __syncthreads();
    }
    if (t < NBLK)
        basem[((size_t)blockIdx.y * NBLK + t) * NBUK + b] =
            bstart[blockIdx.y * NBUK + b] + (s[t] - v);
}

// pass A3: stage records into per-(block,bucket) contiguous runs. Writers of a
// staging line = one block in a short window -> lines merge in L2 (R5-proven).
// record: x = r | (c&511)<<17 (r<2^17), y = raw ew float bits (coefficients are
// computed at placement time — staging happens BEFORE degrees exist).
__global__ __launch_bounds__(256) void k_scat1(const int* ei0, const float* ew0,
                                               const int* ei1, const float* ew1,
                                               const int* basem, int2* st0, int2* st1) {
    __shared__ int lb[NBUK];
    __shared__ int lc[NBUK];
    const int* er = blockIdx.y ? ei1 : ei0;
    const float* ew = blockIdx.y ? ew1 : ew0;
    int2* st = blockIdx.y ? st1 : st0;
    const int* bm = basem + ((size_t)blockIdx.y * NBLK + blockIdx.x) * NBUK;
    for (int i = threadIdx.x; i < NBUK; i += 256) { lb[i] = bm[i]; lc[i] = 0; }
    __syncthreads();
    int base = blockIdx.x * EPB;
    for (int i = 0; i < EPB / 256; i++) {
        int e = base + i * 256 + threadIdx.x;
        if (e >= NE) break;             // e monotone in i -> safe early exit
        int r = er[e];
        int c = er[NE + e];
        float w = ew[e];
        int bkt = c >> 9;
        int rank = atomicAdd(&lc[bkt], 1);
        st[lb[bkt] + rank] = make_int2(r | ((c & 511) << 17), __float_as_int(w));
    }
}

// degrees from staged records: one block per bucket, LDS histogram, zero global
// atomics (replaces k_init_deg + k_count — 130us, 99.8MB of coherence-point
// RMW write traffic, R5 counters).
__global__ __launch_bounds__(256) void k_deg(const int* bstart, const int* btot,
                                             const int2* st0, const int2* st1,
                                             int* deg0, int* deg1) {
    __shared__ int h[NPB];
    int b = blockIdx.x;
    const int2* st = blockIdx.y ? st1 : st0;
    int* deg = blockIdx.y ? deg1 : deg0;
    for (int i = threadIdx.x; i < NPB; i += 256) h[i] = 0;
    __syncthreads();
    int s0 = bstart[blockIdx.y * NBUK + b];
    int tot = btot[blockIdx.y * NBUK + b];
    for (int j = s0 + (int)threadIdx.x; j < s0 + tot; j += 256)
        atomicAdd(&h[(st[j].x >> 17) & 511], 1);
    __syncthreads();
    for (int i = threadIdx.x; i < NPB; i += 256) {
        int node = b * NPB + i;
        if (node < NN) deg[node] = h[i] + 1;   // +1 self-loop
    }
}

// ---------- rowptr scan ----------
__global__ void k_scan1(const int* deg0, const int* deg1, int* rp0, int* rp1s, int* bsum) {
    __shared__ int s[256];
    const int* deg = blockIdx.y ? deg1 : deg0;
    int* rp = (blockIdx.y ? rp1s : rp0) + 1;
    int* bs = bsum + blockIdx.y * 128;
    int tid = threadIdx.x;
    int base = blockIdx.x * 1024 + tid * 4;
    int v0 = 0, v1 = 0, v2 = 0, v3 = 0;
    if (base + 0 < NN) v0 = deg[base + 0];
    if (base + 1 < NN) v1 = deg[base + 1];
    if (base + 2 < NN) v2 = deg[base + 2];
    if (base + 3 < NN) v3 = deg[base + 3];
    int sum = v0 + v1 + v2 + v3;
    s[tid] = sum; __syncthreads();
    for (int off = 1; off < 256; off <<= 1) {
        int t = (tid >= off) ? s[tid - off] : 0;
        __syncthreads(); s[tid] += t; __syncthreads();
    }
    int run = s[tid] - sum;
    if (base + 0 < NN) { run += v0; rp[base + 0] = run; }
    if (base + 1 < NN) { run += v1; rp[base + 1] = run; }
    if (base + 2 < NN) { run += v2; rp[base + 2] = run; }
    if (base + 3 < NN) { run += v3; rp[base + 3] = run; }
    if (tid == 255) bs[blockIdx.x] = s[255];
}

__global__ void k_scan2(int* bsum, int nb) {  // per-block exclusive scan, 2 sets
    __shared__ int s[128];
    int* bs = bsum + blockIdx.x * 128;
    int tid = threadIdx.x;
    int v = (tid < nb) ? bs[tid] : 0;
    s[tid] = v; __syncthreads();
    for (int off = 1; off < 128; off <<= 1) {
        int t = (tid >= off) ? s[tid - off] : 0;
        __syncthreads(); s[tid] += t; __syncthreads();
    }
    if (tid < nb) bs[tid] = s[tid] - v;
}

__global__ void k_scan3(int* rp0, int* rp1s, const int* bsum) {
    int* rowptr = blockIdx.y ? rp1s : rp0;
    int add = bsum[blockIdx.y * 128 + blockIdx.x];
    int tid = threadIdx.x;
    int base = blockIdx.x * 1024 + tid * 4;
    #pragma unroll
    for (int i = 0; i < 4; i++) {
        int idx = base + i;
        if (idx < NN) rowptr[idx + 1] += add;
    }
    if (blockIdx.x == 0 && tid == 0) rowptr[0] = 0;
}

// self-loop in slot rowptr[c] (a = 1/deg = dis^2, b = 1); init dis
__global__ void k_self(const int* rp0, const int* rp1s, const int* deg0, const int* deg1,
                       int2* eo0, int2* eo1, float* dis0, float* dis1) {
    int i = blockIdx.x * 256 + threadIdx.x;
    if (i >= NN) return;
    const int* rowptr = blockIdx.y ? rp1s : rp0;
    const int* deg = blockIdx.y ? deg1 : deg0;
    int2* eo = blockIdx.y ? eo1 : eo0;
    float* dis = blockIdx.y ? dis1 : dis0;
    int p = rowptr[i];
    float d = (float)deg[i];
    eo[p] = make_int2(i, packab(1.0f / d, 1.0f));
    dis[i] = rsqrtf(d);
}

// pass B: one block per bucket; coalesced read of staged slab; coefficients
// computed here (dis now exists); positions via LDS cursors; scatter confined
// to the bucket's ~73KB eo window in a tight window -> L2 merges lines.
__global__ __launch_bounds__(256) void k_scat2(const int* rp0, const int* rp1s,
                                               const int* bstart, const int* btot,
                                               const float* dis0, const float* dis1,
                                               const int2* st0, const int2* st1,
                                               int2* eo0, int2* eo1) {
    __shared__ int lcur[NPB];
    __shared__ float ldis[NPB];
    int b = blockIdx.x;
    const int* rowptr = blockIdx.y ? rp1s : rp0;
    const float* dis = blockIdx.y ? dis1 : dis0;
    const int2* st = blockIdx.y ? st1 : st0;
    int2* eo = blockIdx.y ? eo1 : eo0;
    int nstart = b * NPB;
    for (int i = threadIdx.x; i < NPB; i += 256) {
        int node = nstart + i;
        if (node < NN) { lcur[i] = rowptr[node] + 1; ldis[i] = dis[node]; }
    }
    __syncthreads();
    int s0 = bstart[blockIdx.y * NBUK + b];
    int tot = btot[blockIdx.y * NBUK + b];
    for (int j = s0 + (int)threadIdx.x; j < s0 + tot; j += 256) {
        int2 rec = st[j];
        int cl = (rec.x >> 17) & 511;
        int r  = rec.x & 0x1FFFF;
        float w = __int_as_float(rec.y);
        float a = dis[r] * ldis[cl];          // dis[r]: 400KB L2-resident gather
        float bb = fminf(rsqrtf(w), 1.0f);
        int pos = atomicAdd(&lcur[cl], 1);
        eo[pos] = make_int2(r, packab(a, bb));
    }
}

// ---------- packing ----------
// Xc[N][256] bf16 = [x | d2an | 0-pad]; 4 cols/thread
__global__ void k_packx(const float* x, const float* d2, unsigned short* Xc) {
    int idx = blockIdx.x * 256 + threadIdx.x;   // NN*64 total
    if (idx >= NN * 64) return;
    int r = idx >> 6, k4 = (idx & 63) << 2;
    us4 o;
    if (k4 < 128) {
        float4 v = *(const float4*)(x + (size_t)r * 128 + k4);
        o[0] = f2bf(v.x); o[1] = f2bf(v.y); o[2] = f2bf(v.z); o[3] = f2bf(v.w);
    } else {
        #pragma unroll
        for (int i = 0; i < 4; i++) {
            int k = k4 + i;
            float v = (k < 226) ? d2[(size_t)r * 98 + (k - 128)] : 0.f;
            o[i] = f2bf(v);
        }
    }
    *(us4*)(Xc + (size_t)r * 256 + k4) = o;
}

// All weights packed in one dispatch, MFMA B-fragment order:
// Wf[ks][ct][lane][j] = Worig[c][k], k = ks*32 + (lane>>4)*8 + j, c = ct*16 + (lane&15)
__global__ void k_packw(const float* wn1, const float* wn2,
                        const float* w1a, const float* w1b,
                        const float* w2a, const float* w2b,
                        const float* w3a, const float* w3b,
                        const float* w4a, const float* w4b,
                        unsigned short* Wfnode, unsigned short* WfL) {
    int idx = blockIdx.x * 256 + threadIdx.x;   // 65536 + 4*32768 = 196608
    if (idx < 65536) {
        int j = idx & 7, lane = (idx >> 3) & 63, ct = (idx >> 9) & 15, ks = idx >> 13;
        int k = ks * 32 + (lane >> 4) * 8 + j;
        int c = ct * 16 + (lane & 15);
        float v = 0.f;
        if (k < 226) v = (c < 128) ? wn1[c * 226 + k] : wn2[(c - 128) * 226 + k];
        Wfnode[idx] = f2bf(v);
    } else if (idx < 196608) {
        int li = idx - 65536;
        int set = li >> 15, r = li & 32767;
        const float* wa = (set == 0) ? w1a : (set == 1) ? w2a : (set == 2) ? w3a : w4a;
        const float* wb = (set == 0) ? w1b : (set == 1) ? w2b : (set == 2) ? w3b : w4b;
        int j = r & 7, lane = (r >> 3) & 63, ct = (r >> 9) & 7, ks = r >> 12;
        int k = ks * 32 + (lane >> 4) * 8 + j;
        int c = ct * 16 + (lane & 15);
        float v = (k < 128) ? wa[c * 128 + k] : wb[c * 128 + (k - 128)];
        WfL[li] = f2bf(v);
    }
}

// ---------- aggregation: one wave per node, 16/4/1 ILP tiers ----------
// g1 = sum a_e*S[row_e], g2 = sum b_e*S[row_e]; coefficients in edge record
template <int SRST, int SOFF>
__global__ __launch_bounds__(256) void k_agg(const unsigned short* S,
                                             const int* rowptr, const int2* eg,
                                             unsigned short* G) {
    int c = blockIdx.x * 4 + (threadIdx.x >> 6);
    int lane = threadIdx.x & 63;
    if (c >= NN) return;
    float a0 = 0.f, a1 = 0.f, b0 = 0.f, b1 = 0.f;
    int jb = rowptr[c], je = rowptr[c + 1];
    const unsigned short* Sb = S + SOFF + lane * 2;
    int j = jb;
    for (; j + 16 <= je; j += 16) {
        int2 e[16]; unsigned int u[16];
        #pragma unroll
        for (int i = 0; i < 16; i++) e[i] = eg[j + i];
        #pragma unroll
        for (int i = 0; i < 16; i++)
            u[i] = *(const unsigned int*)(Sb + (size_t)e[i].x * SRST);
        #pragma unroll
        for (int i = 0; i < 16; i++) {
            float2 w = unpackab(e[i].y);
            float x0 = bf2f((unsigned short)(u[i] & 0xFFFF));
            float x1 = bf2f((unsigned short)(u[i] >> 16));
            a0 += w.x * x0; a1 += w.x * x1; b0 += w.y * x0; b1 += w.y * x1;
        }
    }
    for (; j + 4 <= je; j += 4) {
        int2 e[4]; unsigned int u[4];
        #pragma unroll
        for (int i = 0; i < 4; i++) e[i] = eg[j + i];
        #pragma unroll
        for (int i = 0; i < 4; i++)
            u[i] = *(const unsigned int*)(Sb + (size_t)e[i].x * SRST);
        #pragma unroll
        for (int i = 0; i < 4; i++) {
            float2 w = unpackab(e[i].y);
            float x0 = bf2f((unsigned short)(u[i] & 0xFFFF));
            float x1 = bf2f((unsigned short)(u[i] >> 16));
            a0 += w.x * x0; a1 += w.x * x1; b0 += w.y * x0; b1 += w.y * x1;
        }
    }
    for (; j < je; j++) {
        int2 e = eg[j];
        unsigned int u = *(const unsigned int*)(Sb + (size_t)e.x * SRST);
        float2 w = unpackab(e.y);
        float x0 = bf2f((unsigned short)(u & 0xFFFF));
        float x1 = bf2f((unsigned short)(u >> 16));
        a0 += w.x * x0; a1 += w.x * x1; b0 += w.y * x0; b1 += w.y * x1;
    }
    unsigned int* gd = (unsigned int*)(G + (size_t)c * 256);
    gd[lane]      = (unsigned int)f2bf(a0) | ((unsigned int)f2bf(a1) << 16);
    gd[64 + lane] = (unsigned int)f2bf(b0) | ((unsigned int)f2bf(b1) << 16);
}

// ---------- GEMM: C[64 x 128-per-blockIdx.y] = A[N][256] @ Wf, no LDS ----------
// MODE 0: store bf16 plain; 1: store bf16 0.5*relu(T)+0.5*relu(acc); 2: same but f32 to out
template <int MODE>
__global__ __launch_bounds__(256) void k_gemm(const unsigned short* A, int arst,
                                              const unsigned short* Wf, int nct_total,
                                              unsigned short* outB, float* outF,
                                              const unsigned short* T, int orst) {
    int wave = threadIdx.x >> 6, lane = threadIdx.x & 63;
    int m = lane & 15, quad = lane >> 4;
    int row0 = blockIdx.x * 64 + wave * 16;
    int arow = row0 + m;
    bool rowok = arow < NN;
    const unsigned short* Ap = A + (size_t)arow * arst + quad * 8;
    int ctbase = blockIdx.y * 8;
    f32x4 acc[8];
    #pragma unroll
    for (int t = 0; t < 8; t++) acc[t] = (f32x4){0.f, 0.f, 0.f, 0.f};

    #pragma unroll
    for (int ks = 0; ks < 8; ks++) {
        bf16x8 a;
        if (rowok) a = *(const bf16x8*)(Ap + ks * 32);
        else       a = (bf16x8){0, 0, 0, 0, 0, 0, 0, 0};
        const unsigned short* wp = Wf + ((size_t)(ks * nct_total + ctbase) * 64 + lane) * 8;
        #pragma unroll
        for (int t = 0; t < 8; t++) {
            bf16x8 b = *(const bf16x8*)(wp + t * 512);
            acc[t] = __builtin_amdgcn_mfma_f32_16x16x32_bf16(a, b, acc[t], 0, 0, 0);
        }
    }

    int col0 = blockIdx.y * 128;
    #pragma unroll
    for (int t = 0; t < 8; t++) {
        int c = col0 + t * 16 + m;
        #pragma unroll
        for (int rg = 0; rg < 4; rg++) {
            int r = row0 + quad * 4 + rg;
            if (r < NN) {
                float v = acc[t][rg];
                if (MODE == 0) {
                    outB[(size_t)r * orst + c] = f2bf(v);
                } else {
                    float tv = bf2f(T[(size_t)r * 128 + c]);
                    float o = 0.5f * fmaxf(tv, 0.f) + 0.5f * fmaxf(v, 0.f);
                    if (MODE == 1) outB[(size_t)r * orst + c] = f2bf(o);
                    else           outF[(size_t)r * 128 + c] = o;
                }
            }
        }
    }
}

extern "C" void kernel_launch(void* const* d_in, const int* in_sizes, int n_in,
                              void* d_out, int out_size, void* d_ws, size_t ws_size,
                              hipStream_t stream) {
    const float* x      = (const float*)d_in[0];
    const float* d2an   = (const float*)d_in[1];
    const int*   ei0    = (const int*)d_in[2];
    const float* ew0    = (const float*)d_in[3];
    const int*   ei1    = (const int*)d_in[4];
    const float* ew1    = (const float*)d_in[5];
    const float* nodeW1 = (const float*)d_in[6];
    const float* nodeW2 = (const float*)d_in[7];
    const float* W1a = (const float*)d_in[8],  *W1b = (const float*)d_in[9];
    const float* W2a = (const float*)d_in[10], *W2b = (const float*)d_in[11];
    const float* W3a = (const float*)d_in[12], *W3b = (const float*)d_in[13];
    const float* W4a = (const float*)d_in[14], *W4b = (const float*)d_in[15];
    float* out = (float*)d_out;

    // ws carve-out
    char* p = (char*)d_ws;
    auto alloc = [&](size_t bytes) -> char* {
        char* r = p; p += (bytes + 255) & ~(size_t)255; return r;
    };
    unsigned short* bufA   = (unsigned short*)alloc((size_t)NN * 256 * 2); // Xc -> G
    unsigned short* bufB   = (unsigned short*)alloc((size_t)NN * 256 * 2); // stage -> P -> XM
    unsigned short* Tbuf   = (unsigned short*)alloc((size_t)NN * 128 * 2);
    unsigned short* Wfnode = (unsigned short*)alloc(65536 * 2);
    unsigned short* WfL    = (unsigned short*)alloc((size_t)4 * 32768 * 2);
    int*    deg0    = (int*)alloc((size_t)NN * 4);
    int*    deg1    = (int*)alloc((size_t)NN * 4);
    int*    rowptr0 = (int*)alloc((size_t)(NN + 1) * 4);
    int*    rowptr1 = (int*)alloc((size_t)(NN + 1) * 4);
    int*    bsum    = (int*)alloc(2 * 128 * 4);
    float*  dis0    = (float*)alloc((size_t)NN * 4);
    float*  dis1    = (float*)alloc((size_t)NN * 4);
    int2*   eo0     = (int2*)alloc((size_t)ETOT * 8);
    int2*   eo1     = (int2*)alloc((size_t)ETOT * 8);
    int*    cntm    = (int*)alloc((size_t)2 * NBLK * NBUK * 4);
    int*    basem   = (int*)alloc((size_t)2 * NBLK * NBUK * 4);
    int*    btot    = (int*)alloc((size_t)2 * NBUK * 4);
    int*    bstart  = (int*)alloc((size_t)2 * NBUK * 4);

    // staging slabs alias bufB (25.6MB <= 51.2MB); bufB's first real use
    // (k_gemm<0> writing P) is stream-ordered after k_scat2 consumes staging.
    int2* st0 = (int2*)bufB;
    int2* st1 = st0 + NE;

    int nbN  = (NN + 255) / 256;
    int nbS  = (NN + 1023) / 1024;        // 98 scan blocks
    dim3 gP((NN + 63) / 64, 2);           // P gemm: 256 output cols
    dim3 gL((NN + 63) / 64, 1);           // layer gemms: 128 output cols
    int nbA = (NN + 3) / 4;               // agg: 4 waves/block, 1 wave/node

    // --- bucket sort first (staging carries raw ew; no dis dependency) ---
    k_cnt<<<dim3(NBLK, 2), 256, 0, stream>>>(ei0, ei1, cntm);
    k_btot<<<dim3(1, 2), 256, 0, stream>>>(cntm, bstart, btot);
    k_base2<<<dim3(NBUK, 2), 256, 0, stream>>>(cntm, bstart, basem);
    k_scat1<<<dim3(NBLK, 2), 256, 0, stream>>>(ei0, ew0, ei1, ew1, basem, st0, st1);
    // degrees from staged records (LDS-only atomics)
    k_deg<<<dim3(NBUK, 2), 256, 0, stream>>>(bstart, btot, st0, st1, deg0, deg1);
    // rowptr scan
    k_scan1<<<dim3(nbS, 2), 256, 0, stream>>>(deg0, deg1, rowptr0, rowptr1, bsum);
    k_scan2<<<2, 128, 0, stream>>>(bsum, nbS);
    k_scan3<<<dim3(nbS, 2), 256, 0, stream>>>(rowptr0, rowptr1, bsum);
    k_self<<<dim3(nbN, 2), 256, 0, stream>>>(rowptr0, rowptr1, deg0, deg1,
                                             eo0, eo1, dis0, dis1);
    // final placement (computes a,b coefficients; dis now available)
    k_scat2<<<dim3(NBUK, 2), 256, 0, stream>>>(rowptr0, rowptr1, bstart, btot,
                                               dis0, dis1, st0, st1, eo0, eo1);

    // --- packing ---
    k_packx<<<(NN * 64 + 255) / 256, 256, 0, stream>>>(x, d2an, bufA);
    k_packw<<<768, 256, 0, stream>>>(nodeW1, nodeW2, W1a, W1b, W2a, W2b,
                                     W3a, W3b, W4a, W4b, Wfnode, WfL);

    // --- round 1: P = [x|d2an] @ [nodeW1|nodeW2]^T  (bufA=Xc -> bufB=P) ---
    k_gemm<0><<<gP, 256, 0, stream>>>(bufA, 256, Wfnode, 16, bufB, nullptr, nullptr, 256);
    // layer0 (set0 on x0p): agg -> G(bufA); T = g1@W1a^T+g2@W1b^T
    k_agg<256, 0><<<nbA, 256, 0, stream>>>(bufB, rowptr0, eo0, bufA);
    k_gemm<0><<<gL, 256, 0, stream>>>(bufA, 256, WfL, 8, Tbuf, nullptr, nullptr, 128);
    // layer1 (set1 on x1p): agg -> G(bufA); XM = 0.5relu(T)+0.5relu(g@W2) -> bufB
    k_agg<256, 128><<<nbA, 256, 0, stream>>>(bufB, rowptr1, eo1, bufA);
    k_gemm<1><<<gL, 256, 0, stream>>>(bufA, 256, WfL + 32768, 8, bufB, nullptr, Tbuf, 128);

    // --- round 2 on XM (bufB, stride 128) ---
    k_agg<128, 0><<<nbA, 256, 0, stream>>>(bufB, rowptr0, eo0, bufA);
    k_gemm<0><<<gL, 256, 0, stream>>>(bufA, 256, WfL + 2 * 32768, 8, Tbuf, nullptr, nullptr, 128);
    k_agg<128, 0><<<nbA, 256, 0, stream>>>(bufB, rowptr1, eo1, bufA);
    k_gemm<2><<<gL, 256, 0, stream>>>(bufA, 256, WfL + 3 * 32768, 8, nullptr, out, Tbuf, 128);
}